// Round 3
// baseline (2230.338 us; speedup 1.0000x reference)
//
#include <hip/hip_runtime.h>
#include <hip/hip_bf16.h>

#define NNODES 100000
#define NEDGES 1600000
#define IN_F 16
#define HID 128
#define NLAYERS 8
#define BN_EPS 1e-5f
#define BLOBSZ 532480   // ushorts per blob: 8192 + 16*32768 (hi-only since r15)

typedef __attribute__((ext_vector_type(8))) short short8;
typedef __attribute__((ext_vector_type(8))) _Float16 f16x8;
typedef __attribute__((ext_vector_type(4))) float f32x4;
typedef __attribute__((ext_vector_type(4))) unsigned int uint32x4;
typedef unsigned short ushort_t;
typedef unsigned int uint_t;

// ---- fp16 helpers (r14: whole activation chain fp16) ----
__device__ __forceinline__ float f16l(uint_t u) {
  return (float)__builtin_bit_cast(_Float16, (ushort_t)(u & 0xFFFFu));
}
__device__ __forceinline__ float f16h(uint_t u) {
  return (float)__builtin_bit_cast(_Float16, (ushort_t)(u >> 16));
}
__device__ __forceinline__ ushort_t f2h(float f) {
  return __builtin_bit_cast(ushort_t, (_Float16)f);
}
__device__ __forceinline__ uint_t pk16(float x, float y) {
  return (uint_t)f2h(x) | ((uint_t)f2h(y) << 16);
}
__device__ __forceinline__ f16x8 pack8(const float* v) {
  f16x8 r;
#pragma unroll
  for (int j = 0; j < 8; ++j) r[j] = (_Float16)v[j];
  return r;
}

// nontemporal helpers (single-use streams; X0u phase-2 re-reads stay cached)
__device__ __forceinline__ f32x4 ntl4(const float* p) {
  return __builtin_nontemporal_load((const f32x4*)p);
}
__device__ __forceinline__ short8 ntl_s8(const ushort_t* p) {
  return __builtin_nontemporal_load((const short8*)p);
}

// ===================== CSR build: 2-level bucket sort (r8 win) =====================
__global__ __launch_bounds__(256) void bhist_kernel(
    const int* __restrict__ dst, int* __restrict__ bucketCnt, int E, int nbk) {
  __shared__ int cnt[256];
  int t = threadIdx.x;
  cnt[t] = 0;
  __syncthreads();
  int base = blockIdx.x * 2048 + t * 8;
#pragma unroll
  for (int j = 0; j < 8; ++j) {
    int i = base + j;
    if (i < E) atomicAdd(&cnt[dst[i] >> 9], 1);
  }
  __syncthreads();
  if (t < nbk && cnt[t]) atomicAdd(&bucketCnt[t], cnt[t]);
}

__global__ void bscan_kernel(const int* __restrict__ bucketCnt, int* __restrict__ bucketBase,
                             int* __restrict__ bucketCur, int* __restrict__ row_ptr,
                             int N, int E, int nbk) {
  __shared__ int s[256];
  int t = threadIdx.x;
  s[t] = (t < nbk) ? bucketCnt[t] : 0;
  __syncthreads();
  for (int off = 1; off < 256; off <<= 1) {
    int v = (t >= off) ? s[t - off] : 0;
    __syncthreads();
    s[t] += v;
    __syncthreads();
  }
  int excl = (t == 0) ? 0 : s[t - 1];
  if (t < nbk) { bucketBase[t] = excl; bucketCur[t] = excl; }
  if (t == nbk) bucketBase[t] = E;
  if (t == 0) row_ptr[N] = E;
}

__global__ __launch_bounds__(256) void bscatter_kernel(
    const int* __restrict__ src, const int* __restrict__ dst,
    int* __restrict__ bucketCur, int2* __restrict__ ebuf, int E, int nbk) {
  __shared__ int cnt[256];
  __shared__ int base_l[256];
  int t = threadIdx.x;
  cnt[t] = 0;
  __syncthreads();
  int base = blockIdx.x * 2048 + t * 8;
  int bj[8], lr[8], dj[8], sj[8];
#pragma unroll
  for (int j = 0; j < 8; ++j) {
    int i = base + j;
    if (i < E) {
      dj[j] = dst[i];
      sj[j] = src[i];
      bj[j] = dj[j] >> 9;
      lr[j] = atomicAdd(&cnt[bj[j]], 1);
    } else bj[j] = -1;
  }
  __syncthreads();
  if (t < nbk) base_l[t] = cnt[t] ? atomicAdd(&bucketCur[t], cnt[t]) : 0;
  __syncthreads();
#pragma unroll
  for (int j = 0; j < 8; ++j)
    if (bj[j] >= 0) ebuf[base_l[bj[j]] + lr[j]] = make_int2(dj[j], sj[j]);
}

__global__ __launch_bounds__(256) void bcsr_kernel(
    const int2* __restrict__ ebuf, const int* __restrict__ bucketBase,
    int* __restrict__ row_ptr, int* __restrict__ colb, int N) {
  __shared__ int h[512];
  __shared__ int cur[512];
  __shared__ int s2[256];
  int b = blockIdx.x, t = threadIdx.x;
  int beg = bucketBase[b], end = bucketBase[b + 1];
  h[t] = 0; h[t + 256] = 0;
  __syncthreads();
  for (int p = beg + t; p < end; p += 256) atomicAdd(&h[ebuf[p].x & 511], 1);
  __syncthreads();
  s2[t] = h[2 * t] + h[2 * t + 1];
  __syncthreads();
  for (int off = 1; off < 256; off <<= 1) {
    int v = (t >= off) ? s2[t - off] : 0;
    __syncthreads();
    s2[t] += v;
    __syncthreads();
  }
  int ep = (t == 0) ? 0 : s2[t - 1];
  cur[2 * t] = ep;
  cur[2 * t + 1] = ep + h[2 * t];
  int dg = (b << 9) + 2 * t;
  if (dg < N) row_ptr[dg] = beg + cur[2 * t];
  if (dg + 1 < N) row_ptr[dg + 1] = beg + cur[2 * t + 1];
  __syncthreads();
  for (int p = beg + t; p < end; p += 256) {
    int2 e2 = ebuf[p];
    int pos = beg + atomicAdd(&cur[e2.x & 511], 1);
    colb[pos] = e2.y;
  }
}

// =================== weight pre-convert: fp16 MFMA-frag blob (hi only, r15) ===================
__global__ void preconv_kernel(const float* __restrict__ W1_0, const float* __restrict__ W1,
                               const float* __restrict__ W2, const float* __restrict__ Wr1,
                               ushort_t* __restrict__ WB) {
  int g = blockIdx.y;
  int e = blockIdx.x * 256 + threadIdx.x;
  int KP = (g == 0) ? 32 : 128;
  if (e >= KP * 128) return;
  int k = e >> 7, n = e & 127;
  float v;
  if (g == 0) v = (k < 16) ? W1_0[k * 128 + n] : 0.0f;
  else if (g <= 7) v = W1[(size_t)(g - 1) * 16384 + e];
  else if (g <= 15) v = W2[(size_t)(g - 8) * 16384 + e];
  else v = Wr1[e];
  size_t base = (g == 0) ? 0 : (8192 + (size_t)(g - 1) * 32768);
  int unit = ((k >> 5) << 9) + ((n >> 4) << 6) + (n & 15) + (((k >> 3) & 3) << 4);
  WB[base + (size_t)unit * 8 + (k & 7)] = __builtin_bit_cast(ushort_t, (_Float16)v);
}

// ============================ layer-0 aggregation (F=16, fp32) ============================
__global__ __launch_bounds__(256) void agg16_kernel(
    const float* __restrict__ X, const int* __restrict__ rp, const int* __restrict__ colb,
    const float* __restrict__ eps, float* __restrict__ Z, int N) {
  int g = threadIdx.x >> 3;
  int l = threadIdx.x & 7;
  int n = blockIdx.x * 32 + g;
  if (n >= N) return;
  float e = 1.0f + eps[0];
  const float2* X2 = (const float2*)X;
  float2 self = X2[(size_t)n * 8 + l];
  float2 acc = make_float2(self.x * e, self.y * e);
  float2 acc2 = make_float2(0.0f, 0.0f);
  int beg = rp[n], end = rp[n + 1];
  int p = beg;
  for (; p + 4 <= end; p += 4) {
    int s0 = colb[p], s1 = colb[p + 1], s2 = colb[p + 2], s3 = colb[p + 3];
    float2 v0 = X2[(size_t)s0 * 8 + l];
    float2 v1 = X2[(size_t)s1 * 8 + l];
    float2 v2 = X2[(size_t)s2 * 8 + l];
    float2 v3 = X2[(size_t)s3 * 8 + l];
    acc.x += v0.x; acc.y += v0.y;
    acc2.x += v1.x; acc2.y += v1.y;
    acc.x += v2.x; acc.y += v2.y;
    acc2.x += v3.x; acc2.y += v3.y;
  }
  for (; p < end; ++p) {
    int s = colb[p];
    float2 v = X2[(size_t)s * 8 + l];
    acc.x += v.x; acc.y += v.y;
  }
  acc.x += acc2.x; acc.y += acc2.y;
  ((float2*)Z)[(size_t)n * 8 + l] = acc;
}

// layers 1..7 aggregation: Y fp16 gather — r9 structure, near random-gather ceiling.
__global__ __launch_bounds__(256) void agg128_kernel(
    const ushort_t* __restrict__ Y, const float* __restrict__ av, const float* __restrict__ cv,
    const int* __restrict__ rp, const int* __restrict__ colb,
    const float* __restrict__ eps, int layer, uint_t* __restrict__ Z,
    float* __restrict__ SKIP, int smode, int N) {
  int wv = threadIdx.x >> 6;
  int lane = threadIdx.x & 63;
  int n = blockIdx.x * 4 + wv;
  if (n >= N) return;
  float e = 1.0f + eps[layer];
  float2 a2 = *(const float2*)(av + lane * 2);
  float2 c2 = *(const float2*)(cv + lane * 2);
  const uint_t* Yu = (const uint_t*)Y;
  uint_t sv = Yu[(size_t)n * 64 + lane];
  float hx = fmaxf(fmaf(a2.x, f16l(sv), c2.x), 0.0f);
  float hy = fmaxf(fmaf(a2.y, f16h(sv), c2.y), 0.0f);
  if (smode == 1) {
    ((float2*)SKIP)[(size_t)n * 64 + lane] = make_float2(hx, hy);
  } else if (smode == 2) {
    float2* S2 = (float2*)SKIP;
    float2 s = S2[(size_t)n * 64 + lane];
    s.x += hx; s.y += hy;
    S2[(size_t)n * 64 + lane] = s;
  }
  float ax = hx * e, ay = hy * e;
  float bx = 0.0f, by = 0.0f, cx = 0.0f, cy = 0.0f, dx = 0.0f, dy = 0.0f;
  int beg = rp[n], end = rp[n + 1];
  int p = beg;
  for (; p + 8 <= end; p += 8) {
    int s0 = colb[p], s1 = colb[p + 1], s2 = colb[p + 2], s3 = colb[p + 3];
    int s4 = colb[p + 4], s5 = colb[p + 5], s6 = colb[p + 6], s7 = colb[p + 7];
    uint_t v0 = Yu[(size_t)s0 * 64 + lane];
    uint_t v1 = Yu[(size_t)s1 * 64 + lane];
    uint_t v2 = Yu[(size_t)s2 * 64 + lane];
    uint_t v3 = Yu[(size_t)s3 * 64 + lane];
    uint_t v4 = Yu[(size_t)s4 * 64 + lane];
    uint_t v5 = Yu[(size_t)s5 * 64 + lane];
    uint_t v6 = Yu[(size_t)s6 * 64 + lane];
    uint_t v7 = Yu[(size_t)s7 * 64 + lane];
    ax += fmaxf(fmaf(a2.x, f16l(v0), c2.x), 0.0f);
    ay += fmaxf(fmaf(a2.y, f16h(v0), c2.y), 0.0f);
    bx += fmaxf(fmaf(a2.x, f16l(v1), c2.x), 0.0f);
    by += fmaxf(fmaf(a2.y, f16h(v1), c2.y), 0.0f);
    cx += fmaxf(fmaf(a2.x, f16l(v2), c2.x), 0.0f);
    cy += fmaxf(fmaf(a2.y, f16h(v2), c2.y), 0.0f);
    dx += fmaxf(fmaf(a2.x, f16l(v3), c2.x), 0.0f);
    dy += fmaxf(fmaf(a2.y, f16h(v3), c2.y), 0.0f);
    ax += fmaxf(fmaf(a2.x, f16l(v4), c2.x), 0.0f);
    ay += fmaxf(fmaf(a2.y, f16h(v4), c2.y), 0.0f);
    bx += fmaxf(fmaf(a2.x, f16l(v5), c2.x), 0.0f);
    by += fmaxf(fmaf(a2.y, f16h(v5), c2.y), 0.0f);
    cx += fmaxf(fmaf(a2.x, f16l(v6), c2.x), 0.0f);
    cy += fmaxf(fmaf(a2.y, f16h(v6), c2.y), 0.0f);
    dx += fmaxf(fmaf(a2.x, f16l(v7), c2.x), 0.0f);
    dy += fmaxf(fmaf(a2.y, f16h(v7), c2.y), 0.0f);
  }
  for (; p < end; ++p) {
    int s = colb[p];
    uint_t v = Yu[(size_t)s * 64 + lane];
    ax += fmaxf(fmaf(a2.x, f16l(v), c2.x), 0.0f);
    ay += fmaxf(fmaf(a2.y, f16h(v), c2.y), 0.0f);
  }
  ax += bx + cx + dx;
  ay += by + cy + dy;
  Z[(size_t)n * 64 + lane] = pk16(ax, ay);
}

// ======================= r16: fused GEMM pair with BN grid barrier =======================
// gemm1 (Z -> H1, inner BN stats) and gemm2 (relu(BN(H1)) -> Y, outer BN stats) fused into
// ONE kernel. Block b's phase-2 A-tile is exactly the tile block b wrote in phase 1 -> the
// only cross-block dependency is the 256 BN scalars. Last block publishes pa/pc via
// device-scope atomic stores + release flag; all blocks spin-acquire then broadcast via LDS.
// Deadlock-safe: __launch_bounds__(256,4) forces <=128 VGPR -> 4 blocks/CU -> 1024 resident
// slots >= 782 blocks. Phase-2 A re-read hits own-XCD L2 (own phase-1 stores).
// MODE1 == 3: phase-1 A = fp32 [M][16] (layer 0, K=32 pad). MODE1 == 0: A = X0u in place.
template <int MODE1>
__global__ __launch_bounds__(256, 4) void gemm_pair(
    const float* __restrict__ A, ushort_t* __restrict__ X0u,
    const ushort_t* __restrict__ Bh1, const float* __restrict__ bias1,
    const ushort_t* __restrict__ Bh2, const float* __restrict__ bias2,
    ushort_t* __restrict__ YB,
    float* __restrict__ gsum1, float* __restrict__ gsq1, int* __restrict__ cnt1,
    int* __restrict__ flag1, float* __restrict__ pa1, float* __restrict__ pc1,
    const float* __restrict__ g1, const float* __restrict__ be1,
    float* __restrict__ gsum2, float* __restrict__ gsq2,
    float* __restrict__ aout2, float* __restrict__ cout2, int* __restrict__ cnt2,
    const float* __restrict__ g2, const float* __restrict__ be2,
    float invN, int M, int nb) {
  __shared__ float s_part[4][256];
  __shared__ float s_papc[256];
  __shared__ int s_last;
  const int tid = threadIdx.x;
  const int w = tid >> 6;
  const int lane = tid & 63;
  const int ln = lane & 15;
  const int quad = lane >> 4;
  const int brow = blockIdx.x * 128;

  int r0 = brow + (w << 5) + ln;       if (r0 >= M) r0 = M - 1;
  int r1 = brow + (w << 5) + 16 + ln;  if (r1 >= M) r1 = M - 1;

  f32x4 acc[2][8];
#pragma unroll
  for (int rt = 0; rt < 2; ++rt)
#pragma unroll
    for (int ct = 0; ct < 8; ++ct) acc[rt][ct] = (f32x4){0.0f, 0.0f, 0.0f, 0.0f};

  // ---------------- phase 1: Z @ W1 -> H1 ----------------
  constexpr int KC1 = (MODE1 == 3) ? 1 : 4;
#pragma unroll
  for (int kcl = 0; kcl < KC1; ++kcl) {
    const int kb = (kcl << 5) + (quad << 3);
    f16x8 af0, af1;
    if constexpr (MODE1 == 3) {
      if (kb < 16) {
        f32x4 a0 = ntl4(A + (size_t)r0 * 16 + kb);
        f32x4 a1 = ntl4(A + (size_t)r0 * 16 + kb + 4);
        f32x4 b0 = ntl4(A + (size_t)r1 * 16 + kb);
        f32x4 b1 = ntl4(A + (size_t)r1 * 16 + kb + 4);
        float e0[8] = {a0.x, a0.y, a0.z, a0.w, a1.x, a1.y, a1.z, a1.w};
        float e1[8] = {b0.x, b0.y, b0.z, b0.w, b1.x, b1.y, b1.z, b1.w};
        af0 = pack8(e0);
        af1 = pack8(e1);
      } else {
#pragma unroll
        for (int j = 0; j < 8; ++j) { af0[j] = (_Float16)0.0f; af1[j] = (_Float16)0.0f; }
      }
    } else {
      af0 = __builtin_bit_cast(f16x8, ntl_s8(X0u + (size_t)r0 * 128 + kb));
      af1 = __builtin_bit_cast(f16x8, ntl_s8(X0u + (size_t)r1 * 128 + kb));
    }
    const ushort_t* bh_base = Bh1 + (((size_t)(kcl << 9) + lane) << 3);
#pragma unroll
    for (int ct = 0; ct < 8; ++ct) {
      f16x8 bh = __builtin_bit_cast(f16x8, *(const short8*)(bh_base + (ct << 9)));
      acc[0][ct] = __builtin_amdgcn_mfma_f32_16x16x32_f16(af0, bh, acc[0][ct], 0, 0, 0);
      acc[1][ct] = __builtin_amdgcn_mfma_f32_16x16x32_f16(af1, bh, acc[1][ct], 0, 0, 0);
    }
  }

  // phase-1 epilogue: bias, H1 store (fp16, cached — we re-read it), stats
#pragma unroll
  for (int ct = 0; ct < 8; ++ct) {
    int col = (ct << 4) + ln;
    float bsc = bias1[col];
    float csum = 0.0f, csq = 0.0f;
#pragma unroll
    for (int rt = 0; rt < 2; ++rt) {
#pragma unroll
      for (int i = 0; i < 4; ++i) {
        int row = brow + (w << 5) + (rt << 4) + (quad << 2) + i;
        if (row < M) {
          float y = acc[rt][ct][i] + bsc;
          csum += y; csq += y * y;
          X0u[(size_t)row * 128 + col] = f2h(y);
        }
      }
    }
    csum += __shfl_xor(csum, 16, 64);
    csum += __shfl_xor(csum, 32, 64);
    csq += __shfl_xor(csq, 16, 64);
    csq += __shfl_xor(csq, 32, 64);
    if (quad == 0) {
      s_part[w][col] = csum;
      s_part[w][128 + col] = csq;
    }
  }
  __syncthreads();
  if (tid < 128) {
    float s = s_part[0][tid] + s_part[1][tid] + s_part[2][tid] + s_part[3][tid];
    float q = s_part[0][128 + tid] + s_part[1][128 + tid] +
              s_part[2][128 + tid] + s_part[3][128 + tid];
    atomicAdd(&gsum1[tid], s);
    atomicAdd(&gsq1[tid], q);
  }
  __syncthreads();   // drains vmcnt -> stats atomics + H1 stores complete
  if (tid == 0) {
    int v = __hip_atomic_fetch_add(cnt1, 1, __ATOMIC_RELAXED, __HIP_MEMORY_SCOPE_AGENT);
    s_last = (v == nb - 1) ? 1 : 0;
  }
  __syncthreads();
  if (s_last) {
    if (tid < 128) {
      float s = __hip_atomic_load(&gsum1[tid], __ATOMIC_RELAXED, __HIP_MEMORY_SCOPE_AGENT);
      float q = __hip_atomic_load(&gsq1[tid], __ATOMIC_RELAXED, __HIP_MEMORY_SCOPE_AGENT);
      float mu = s * invN;
      float var = q * invN - mu * mu;
      float sc = g1[tid] * rsqrtf(var + BN_EPS);
      __hip_atomic_store(&pa1[tid], sc, __ATOMIC_RELAXED, __HIP_MEMORY_SCOPE_AGENT);
      __hip_atomic_store(&pc1[tid], be1[tid] - sc * mu, __ATOMIC_RELAXED,
                         __HIP_MEMORY_SCOPE_AGENT);
    }
    __syncthreads();  // drain atomic stores before release
    if (tid == 0)
      __hip_atomic_store(flag1, 1, __ATOMIC_RELEASE, __HIP_MEMORY_SCOPE_AGENT);
  }
  if (tid == 0) {
    while (__hip_atomic_load(flag1, __ATOMIC_ACQUIRE, __HIP_MEMORY_SCOPE_AGENT) == 0)
      __builtin_amdgcn_s_sleep(16);
  }
  __syncthreads();
  s_papc[tid] = (tid < 128)
      ? __hip_atomic_load(&pa1[tid], __ATOMIC_RELAXED, __HIP_MEMORY_SCOPE_AGENT)
      : __hip_atomic_load(&pc1[tid - 128], __ATOMIC_RELAXED, __HIP_MEMORY_SCOPE_AGENT);
  __syncthreads();

  // ---------------- phase 2: relu(BN(H1)) @ W2 -> Y ----------------
#pragma unroll
  for (int rt = 0; rt < 2; ++rt)
#pragma unroll
    for (int ct = 0; ct < 8; ++ct) acc[rt][ct] = (f32x4){0.0f, 0.0f, 0.0f, 0.0f};

#pragma unroll
  for (int kcl = 0; kcl < 4; ++kcl) {
    const int kb = (kcl << 5) + (quad << 3);
    uint32x4 xa = *(const uint32x4*)(X0u + (size_t)r0 * 128 + kb);
    uint32x4 xb = *(const uint32x4*)(X0u + (size_t)r1 * 128 + kb);
    float pp[8], qq[8];
#pragma unroll
    for (int j = 0; j < 8; ++j) {
      pp[j] = s_papc[kb + j];
      qq[j] = s_papc[128 + kb + j];
    }
    float e0[8] = {f16l(xa.x), f16h(xa.x), f16l(xa.y), f16h(xa.y),
                   f16l(xa.z), f16h(xa.z), f16l(xa.w), f16h(xa.w)};
    float e1[8] = {f16l(xb.x), f16h(xb.x), f16l(xb.y), f16h(xb.y),
                   f16l(xb.z), f16h(xb.z), f16l(xb.w), f16h(xb.w)};
#pragma unroll
    for (int j = 0; j < 8; ++j) {
      e0[j] = fmaxf(fmaf(pp[j], e0[j], qq[j]), 0.0f);
      e1[j] = fmaxf(fmaf(pp[j], e1[j], qq[j]), 0.0f);
    }
    f16x8 af0 = pack8(e0);
    f16x8 af1 = pack8(e1);
    const ushort_t* bh_base = Bh2 + (((size_t)(kcl << 9) + lane) << 3);
#pragma unroll
    for (int ct = 0; ct < 8; ++ct) {
      f16x8 bh = __builtin_bit_cast(f16x8, *(const short8*)(bh_base + (ct << 9)));
      acc[0][ct] = __builtin_amdgcn_mfma_f32_16x16x32_f16(af0, bh, acc[0][ct], 0, 0, 0);
      acc[1][ct] = __builtin_amdgcn_mfma_f32_16x16x32_f16(af1, bh, acc[1][ct], 0, 0, 0);
    }
  }

  // phase-2 epilogue: bias, Y store (fp16), outer-BN stats + cross-kernel finalize
#pragma unroll
  for (int ct = 0; ct < 8; ++ct) {
    int col = (ct << 4) + ln;
    float bsc = bias2[col];
    float csum = 0.0f, csq = 0.0f;
#pragma unroll
    for (int rt = 0; rt < 2; ++rt) {
#pragma unroll
      for (int i = 0; i < 4; ++i) {
        int row = brow + (w << 5) + (rt << 4) + (quad << 2) + i;
        if (row < M) {
          float y = acc[rt][ct][i] + bsc;
          csum += y; csq += y * y;
          YB[(size_t)row * 128 + col] = f2h(y);
        }
      }
    }
    csum += __shfl_xor(csum, 16, 64);
    csum += __shfl_xor(csum, 32, 64);
    csq += __shfl_xor(csq, 16, 64);
    csq += __shfl_xor(csq, 32, 64);
    if (quad == 0) {
      s_part[w][col] = csum;
      s_part[w][128 + col] = csq;
    }
  }
  __syncthreads();
  if (tid < 128) {
    float s = s_part[0][tid] + s_part[1][tid] + s_part[2][tid] + s_part[3][tid];
    float q = s_part[0][128 + tid] + s_part[1][128 + tid] +
              s_part[2][128 + tid] + s_part[3][128 + tid];
    atomicAdd(&gsum2[tid], s);
    atomicAdd(&gsq2[tid], q);
  }
  __syncthreads();
  if (tid == 0) {
    int v = __hip_atomic_fetch_add(cnt2, 1, __ATOMIC_RELAXED, __HIP_MEMORY_SCOPE_AGENT);
    s_last = (v == nb - 1) ? 1 : 0;
  }
  __syncthreads();
  if (s_last && tid < 128) {
    float s = __hip_atomic_load(&gsum2[tid], __ATOMIC_RELAXED, __HIP_MEMORY_SCOPE_AGENT);
    float q = __hip_atomic_load(&gsq2[tid], __ATOMIC_RELAXED, __HIP_MEMORY_SCOPE_AGENT);
    float mu = s * invN;
    float var = q * invN - mu * mu;
    float sc = g2[tid] * rsqrtf(var + BN_EPS);
    aout2[tid] = sc;                  // next kernel reads across boundary (coherent)
    cout2[tid] = be2[tid] - sc * mu;
  }
}

// =================== r16: fused regressor head (GEMM + BN + dot + sigmoid) ===================
// Phase 1 = old MODE 2 GEMM (0.25*(SKIP + relu(a7*Y7+c7)) @ Wr1), stats; barrier; phase 2
// applies BN+relu IN REGISTERS and reduces against Wr2 -> out. Kills the 51 MB fp32 X0
// write + re-read and the finaldot dispatch entirely.
__global__ __launch_bounds__(256, 4) void gemm_head(
    const float* __restrict__ SKIP, const ushort_t* __restrict__ Y7,
    const ushort_t* __restrict__ Bh, const float* __restrict__ bias,
    const float* __restrict__ pa7, const float* __restrict__ pc7,
    float* __restrict__ gsum, float* __restrict__ gsq, int* __restrict__ cnt,
    int* __restrict__ flag, float* __restrict__ pa, float* __restrict__ pc,
    const float* __restrict__ gr, const float* __restrict__ ber,
    const float* __restrict__ Wr2, const float* __restrict__ br2,
    float* __restrict__ out, float invN, int M, int nb) {
  __shared__ float s_part[4][256];
  __shared__ float s_papc[256];
  __shared__ int s_last;
  const int tid = threadIdx.x;
  const int w = tid >> 6;
  const int lane = tid & 63;
  const int ln = lane & 15;
  const int quad = lane >> 4;
  const int brow = blockIdx.x * 128;

  int r0 = brow + (w << 5) + ln;       if (r0 >= M) r0 = M - 1;
  int r1 = brow + (w << 5) + 16 + ln;  if (r1 >= M) r1 = M - 1;

  f32x4 acc[2][8];
#pragma unroll
  for (int rt = 0; rt < 2; ++rt)
#pragma unroll
    for (int ct = 0; ct < 8; ++ct) acc[rt][ct] = (f32x4){0.0f, 0.0f, 0.0f, 0.0f};

#pragma unroll
  for (int kcl = 0; kcl < 4; ++kcl) {
    const int kb = (kcl << 5) + (quad << 3);
    f32x4 a0 = ntl4(SKIP + (size_t)r0 * 128 + kb);
    f32x4 a1 = ntl4(SKIP + (size_t)r0 * 128 + kb + 4);
    f32x4 b0 = ntl4(SKIP + (size_t)r1 * 128 + kb);
    f32x4 b1 = ntl4(SKIP + (size_t)r1 * 128 + kb + 4);
    float s0[8] = {a0.x, a0.y, a0.z, a0.w, a1.x, a1.y, a1.z, a1.w};
    float s1[8] = {b0.x, b0.y, b0.z, b0.w, b1.x, b1.y, b1.z, b1.w};
    uint32x4 ya = *(const uint32x4*)(Y7 + (size_t)r0 * 128 + kb);
    uint32x4 yb = *(const uint32x4*)(Y7 + (size_t)r1 * 128 + kb);
    float4 p0 = *(const float4*)(pa7 + kb);
    float4 p1 = *(const float4*)(pa7 + kb + 4);
    float4 q0 = *(const float4*)(pc7 + kb);
    float4 q1 = *(const float4*)(pc7 + kb + 4);
    float pp[8] = {p0.x, p0.y, p0.z, p0.w, p1.x, p1.y, p1.z, p1.w};
    float qq[8] = {q0.x, q0.y, q0.z, q0.w, q1.x, q1.y, q1.z, q1.w};
    float y0a[8] = {f16l(ya.x), f16h(ya.x), f16l(ya.y), f16h(ya.y),
                    f16l(ya.z), f16h(ya.z), f16l(ya.w), f16h(ya.w)};
    float y1a[8] = {f16l(yb.x), f16h(yb.x), f16l(yb.y), f16h(yb.y),
                    f16l(yb.z), f16h(yb.z), f16l(yb.w), f16h(yb.w)};
    float e0[8], e1[8];
#pragma unroll
    for (int j = 0; j < 8; ++j) {
      e0[j] = 0.25f * (s0[j] + fmaxf(fmaf(pp[j], y0a[j], qq[j]), 0.0f));
      e1[j] = 0.25f * (s1[j] + fmaxf(fmaf(pp[j], y1a[j], qq[j]), 0.0f));
    }
    f16x8 af0 = pack8(e0);
    f16x8 af1 = pack8(e1);
    const ushort_t* bh_base = Bh + (((size_t)(kcl << 9) + lane) << 3);
#pragma unroll
    for (int ct = 0; ct < 8; ++ct) {
      f16x8 bh = __builtin_bit_cast(f16x8, *(const short8*)(bh_base + (ct << 9)));
      acc[0][ct] = __builtin_amdgcn_mfma_f32_16x16x32_f16(af0, bh, acc[0][ct], 0, 0, 0);
      acc[1][ct] = __builtin_amdgcn_mfma_f32_16x16x32_f16(af1, bh, acc[1][ct], 0, 0, 0);
    }
  }

  // stats (no C store — acc stays in registers across the barrier)
#pragma unroll
  for (int ct = 0; ct < 8; ++ct) {
    int col = (ct << 4) + ln;
    float bsc = bias[col];
    float csum = 0.0f, csq = 0.0f;
#pragma unroll
    for (int rt = 0; rt < 2; ++rt) {
#pragma unroll
      for (int i = 0; i < 4; ++i) {
        int row = brow + (w << 5) + (rt << 4) + (quad << 2) + i;
        if (row < M) {
          float y = acc[rt][ct][i] + bsc;
          csum += y; csq += y * y;
        }
      }
    }
    csum += __shfl_xor(csum, 16, 64);
    csum += __shfl_xor(csum, 32, 64);
    csq += __shfl_xor(csq, 16, 64);
    csq += __shfl_xor(csq, 32, 64);
    if (quad == 0) {
      s_part[w][col] = csum;
      s_part[w][128 + col] = csq;
    }
  }
  __syncthreads();
  if (tid < 128) {
    float s = s_part[0][tid] + s_part[1][tid] + s_part[2][tid] + s_part[3][tid];
    float q = s_part[0][128 + tid] + s_part[1][128 + tid] +
              s_part[2][128 + tid] + s_part[3][128 + tid];
    atomicAdd(&gsum[tid], s);
    atomicAdd(&gsq[tid], q);
  }
  __syncthreads();
  if (tid == 0) {
    int v = __hip_atomic_fetch_add(cnt, 1, __ATOMIC_RELAXED, __HIP_MEMORY_SCOPE_AGENT);
    s_last = (v == nb - 1) ? 1 : 0;
  }
  __syncthreads();
  if (s_last) {
    if (tid < 128) {
      float s = __hip_atomic_load(&gsum[tid], __ATOMIC_RELAXED, __HIP_MEMORY_SCOPE_AGENT);
      float q = __hip_atomic_load(&gsq[tid], __ATOMIC_RELAXED, __HIP_MEMORY_SCOPE_AGENT);
      float mu = s * invN;
      float var = q * invN - mu * mu;
      float sc = gr[tid] * rsqrtf(var + BN_EPS);
      __hip_atomic_store(&pa[tid], sc, __ATOMIC_RELAXED, __HIP_MEMORY_SCOPE_AGENT);
      __hip_atomic_store(&pc[tid], ber[tid] - sc * mu, __ATOMIC_RELAXED,
                         __HIP_MEMORY_SCOPE_AGENT);
    }
    __syncthreads();
    if (tid == 0)
      __hip_atomic_store(flag, 1, __ATOMIC_RELEASE, __HIP_MEMORY_SCOPE_AGENT);
  }
  if (tid == 0) {
    while (__hip_atomic_load(flag, __ATOMIC_ACQUIRE, __HIP_MEMORY_SCOPE_AGENT) == 0)
      __builtin_amdgcn_s_sleep(16);
  }
  __syncthreads();
  s_papc[tid] = (tid < 128)
      ? __hip_atomic_load(&pa[tid], __ATOMIC_RELAXED, __HIP_MEMORY_SCOPE_AGENT)
      : __hip_atomic_load(&pc[tid - 128], __ATOMIC_RELAXED, __HIP_MEMORY_SCOPE_AGENT);
  __syncthreads();

  // phase 2: out[row] = sigmoid(sum_col relu(pa*y+pc) * Wr2[col] + br2)
  float br2v = br2[0];
#pragma unroll
  for (int rt = 0; rt < 2; ++rt) {
#pragma unroll
    for (int i = 0; i < 4; ++i) {
      float s = 0.0f;
#pragma unroll
      for (int ct = 0; ct < 8; ++ct) {
        int col = (ct << 4) + ln;
        float y = acc[rt][ct][i] + bias[col];
        s += fmaxf(fmaf(s_papc[col], y, s_papc[128 + col]), 0.0f) * Wr2[col];
      }
      s += __shfl_xor(s, 1, 64);
      s += __shfl_xor(s, 2, 64);
      s += __shfl_xor(s, 4, 64);
      s += __shfl_xor(s, 8, 64);
      int row = brow + (w << 5) + (rt << 4) + (quad << 2) + i;
      if (ln == 0 && row < M) out[row] = 1.0f / (1.0f + expf(-(s + br2v)));
    }
  }
}

// ============================ launch ============================
extern "C" void kernel_launch(void* const* d_in, const int* in_sizes, int n_in,
                              void* d_out, int out_size, void* d_ws, size_t ws_size,
                              hipStream_t stream) {
  const float* x     = (const float*)d_in[0];
  const int*   ei    = (const int*)d_in[1];
  const float* eps   = (const float*)d_in[2];
  const float* W1_0  = (const float*)d_in[3];
  const float* b1_0  = (const float*)d_in[4];
  const float* W1    = (const float*)d_in[5];
  const float* b1    = (const float*)d_in[6];
  const float* g_in  = (const float*)d_in[7];
  const float* be_in = (const float*)d_in[8];
  const float* W2    = (const float*)d_in[9];
  const float* b2    = (const float*)d_in[10];
  const float* g_out = (const float*)d_in[11];
  const float* be_out= (const float*)d_in[12];
  const float* Wr1   = (const float*)d_in[13];
  const float* br1   = (const float*)d_in[14];
  const float* gr    = (const float*)d_in[15];
  const float* ber   = (const float*)d_in[16];
  const float* Wr2   = (const float*)d_in[17];
  const float* br2   = (const float*)d_in[18];
  float* out = (float*)d_out;

  const int N = in_sizes[0] / IN_F;   // 100000
  const int E = in_sizes[1] / 2;      // 1600000
  const int* srcv = ei;
  const int* dstv = ei + E;
  const int nbk = (N + 511) >> 9;     // 196 buckets

  // workspace carve
  float* X0    = (float*)d_ws;                  // [N][128] fp32-sized (fp16 Z/H1)
  float* SKIP  = X0 + (size_t)N * HID;          // [N][128] fp32 (L0 [N,16] temp, then skip)
  ushort_t* YB = (ushort_t*)(SKIP + (size_t)N * HID);  // [N][128] fp16 Y (hot gather target)
  int* colb    = (int*)(YB + (size_t)N * HID);
  int* row_ptr = colb + E;
  int2* ebuf   = (int2*)(row_ptr + (N + 4));
  int* bucketCnt  = (int*)(ebuf + E);
  int* bucketBase = bucketCnt + 256;
  int* bucketCur  = bucketBase + 260;
  float* arena = (float*)(bucketCur + 256);     // 17 slots x 640 floats
  ushort_t* WB = (ushort_t*)(arena + 17 * 640); // hi blob (fp16)
  ushort_t* X0u = (ushort_t*)X0;

  hipMemsetAsync(bucketCnt, 0, sizeof(int) * 256, stream);
  hipMemsetAsync(arena, 0, sizeof(float) * 17 * 640, stream);

  // CSR build (bucket sort)
  int nbE = (E + 2047) / 2048;
  bhist_kernel<<<nbE, 256, 0, stream>>>(dstv, bucketCnt, E, nbk);
  bscan_kernel<<<1, 256, 0, stream>>>(bucketCnt, bucketBase, bucketCur, row_ptr, N, E, nbk);
  bscatter_kernel<<<nbE, 256, 0, stream>>>(srcv, dstv, bucketCur, ebuf, E, nbk);
  bcsr_kernel<<<nbk, 256, 0, stream>>>(ebuf, bucketBase, row_ptr, colb, N);
  preconv_kernel<<<dim3(64, 17), 256, 0, stream>>>(W1_0, W1, W2, Wr1, WB);

  const int gg = (N + 127) / 128;   // 782 tiles; 4 blk/CU * 256 CU = 1024 slots >= 782
  const float invN = 1.0f / (float)N;
#define SLOT(s) (arena + (s) * 640)
#define SSUM(s) SLOT(s)
#define SSQ(s)  (SLOT(s) + 128)
#define SA(s)   (SLOT(s) + 256)
#define SC(s)   (SLOT(s) + 384)
#define SCNT(s) ((int*)(SLOT(s) + 512))
#define SFLG(s) ((int*)(SLOT(s) + 513))
#define WBH(g)  (WB + ((g) == 0 ? 0 : (8192 + (size_t)((g) - 1) * 32768)))

  // ---- layer 0 (fused pair): agg16: x -> SKIP[N,16]; pair: SKIP -> X0u -> YB ----
  agg16_kernel<<<(N + 31) / 32, 256, 0, stream>>>(x, row_ptr, colb, eps, SKIP, N);
  gemm_pair<3><<<gg, 256, 0, stream>>>(
      SKIP, X0u, WBH(0), b1_0, WBH(8), b2, YB,
      SSUM(0), SSQ(0), SCNT(0), SFLG(0), SA(0), SC(0), g_in, be_in,
      SSUM(1), SSQ(1), SA(1), SC(1), SCNT(1), g_out, be_out, invN, N, gg);
  // No SKIP memset: L=2's agg does a plain store (smode=1) covering all N*128 elements.

  // ---- layers 1..7 (fused pairs) ----
  for (int L = 1; L < NLAYERS; ++L) {
    int sp = 2 * L - 1;
    int s0 = 2 * L, s1 = 2 * L + 1;
    int smode = ((L - 1) & 1) ? ((L == 2) ? 1 : 2) : 0;
    agg128_kernel<<<(N + 3) / 4, 256, 0, stream>>>(
        YB, SA(sp), SC(sp), row_ptr, colb, eps, L, (uint_t*)X0u, SKIP, smode, N);
    gemm_pair<0><<<gg, 256, 0, stream>>>(
        nullptr, X0u, WBH(L), b1 + (size_t)(L - 1) * HID, WBH(8 + L), b2 + (size_t)L * HID, YB,
        SSUM(s0), SSQ(s0), SCNT(s0), SFLG(s0), SA(s0), SC(s0),
        g_in + (size_t)L * HID, be_in + (size_t)L * HID,
        SSUM(s1), SSQ(s1), SA(s1), SC(s1), SCNT(s1),
        g_out + (size_t)L * HID, be_out + (size_t)L * HID, invN, N, gg);
  }
  // Y7 in YB (fp16), slot 15 holds its outer-BN params

  // ---- fused regressor head ----
  gemm_head<<<gg, 256, 0, stream>>>(
      SKIP, YB, WBH(16), br1, SA(15), SC(15),
      SSUM(16), SSQ(16), SCNT(16), SFLG(16), SA(16), SC(16),
      gr, ber, Wr2, br2, out, invN, N, gg);
#undef SLOT
#undef SSUM
#undef SSQ
#undef SA
#undef SC
#undef SCNT
#undef SFLG
#undef WBH
}

// Round 4
// 1523.175 us; speedup vs baseline: 1.4643x; 1.4643x over previous
//
#include <hip/hip_runtime.h>
#include <hip/hip_bf16.h>

#define NNODES 100000
#define NEDGES 1600000
#define IN_F 16
#define HID 128
#define NLAYERS 8
#define BN_EPS 1e-5f
#define BLOBSZ 532480   // ushorts per blob: 8192 + 16*32768 (hi-only since r15)

typedef __attribute__((ext_vector_type(8))) short short8;
typedef __attribute__((ext_vector_type(8))) _Float16 f16x8;
typedef __attribute__((ext_vector_type(4))) float f32x4;
typedef __attribute__((ext_vector_type(4))) unsigned int uint32x4;
typedef unsigned short ushort_t;
typedef unsigned int uint_t;

// ---- fp16 helpers (r14: whole activation chain fp16) ----
__device__ __forceinline__ float f16l(uint_t u) {
  return (float)__builtin_bit_cast(_Float16, (ushort_t)(u & 0xFFFFu));
}
__device__ __forceinline__ float f16h(uint_t u) {
  return (float)__builtin_bit_cast(_Float16, (ushort_t)(u >> 16));
}
__device__ __forceinline__ ushort_t f2h(float f) {
  return __builtin_bit_cast(ushort_t, (_Float16)f);
}
__device__ __forceinline__ uint_t pk16(float x, float y) {
  return (uint_t)f2h(x) | ((uint_t)f2h(y) << 16);
}
__device__ __forceinline__ f16x8 pack8(const float* v) {
  f16x8 r;
#pragma unroll
  for (int j = 0; j < 8; ++j) r[j] = (_Float16)v[j];
  return r;
}

// nontemporal helpers (streams with no reuse; YB/X0u stay cached for reuse)
__device__ __forceinline__ f32x4 ntl4(const float* p) {
  return __builtin_nontemporal_load((const f32x4*)p);
}
__device__ __forceinline__ short8 ntl_s8(const ushort_t* p) {
  return __builtin_nontemporal_load((const short8*)p);
}
__device__ __forceinline__ void nts1(float v, float* p) {
  __builtin_nontemporal_store(v, p);
}

// ===================== CSR build: 2-level bucket sort (r8 win) =====================
__global__ __launch_bounds__(256) void bhist_kernel(
    const int* __restrict__ dst, int* __restrict__ bucketCnt, int E, int nbk) {
  __shared__ int cnt[256];
  int t = threadIdx.x;
  cnt[t] = 0;
  __syncthreads();
  int base = blockIdx.x * 2048 + t * 8;
#pragma unroll
  for (int j = 0; j < 8; ++j) {
    int i = base + j;
    if (i < E) atomicAdd(&cnt[dst[i] >> 9], 1);
  }
  __syncthreads();
  if (t < nbk && cnt[t]) atomicAdd(&bucketCnt[t], cnt[t]);
}

__global__ void bscan_kernel(const int* __restrict__ bucketCnt, int* __restrict__ bucketBase,
                             int* __restrict__ bucketCur, int* __restrict__ row_ptr,
                             int N, int E, int nbk) {
  __shared__ int s[256];
  int t = threadIdx.x;
  s[t] = (t < nbk) ? bucketCnt[t] : 0;
  __syncthreads();
  for (int off = 1; off < 256; off <<= 1) {
    int v = (t >= off) ? s[t - off] : 0;
    __syncthreads();
    s[t] += v;
    __syncthreads();
  }
  int excl = (t == 0) ? 0 : s[t - 1];
  if (t < nbk) { bucketBase[t] = excl; bucketCur[t] = excl; }
  if (t == nbk) bucketBase[t] = E;
  if (t == 0) row_ptr[N] = E;
}

__global__ __launch_bounds__(256) void bscatter_kernel(
    const int* __restrict__ src, const int* __restrict__ dst,
    int* __restrict__ bucketCur, int2* __restrict__ ebuf, int E, int nbk) {
  __shared__ int cnt[256];
  __shared__ int base_l[256];
  int t = threadIdx.x;
  cnt[t] = 0;
  __syncthreads();
  int base = blockIdx.x * 2048 + t * 8;
  int bj[8], lr[8], dj[8], sj[8];
#pragma unroll
  for (int j = 0; j < 8; ++j) {
    int i = base + j;
    if (i < E) {
      dj[j] = dst[i];
      sj[j] = src[i];
      bj[j] = dj[j] >> 9;
      lr[j] = atomicAdd(&cnt[bj[j]], 1);
    } else bj[j] = -1;
  }
  __syncthreads();
  if (t < nbk) base_l[t] = cnt[t] ? atomicAdd(&bucketCur[t], cnt[t]) : 0;
  __syncthreads();
#pragma unroll
  for (int j = 0; j < 8; ++j)
    if (bj[j] >= 0) ebuf[base_l[bj[j]] + lr[j]] = make_int2(dj[j], sj[j]);
}

__global__ __launch_bounds__(256) void bcsr_kernel(
    const int2* __restrict__ ebuf, const int* __restrict__ bucketBase,
    int* __restrict__ row_ptr, int* __restrict__ colb, int N) {
  __shared__ int h[512];
  __shared__ int cur[512];
  __shared__ int s2[256];
  int b = blockIdx.x, t = threadIdx.x;
  int beg = bucketBase[b], end = bucketBase[b + 1];
  h[t] = 0; h[t + 256] = 0;
  __syncthreads();
  for (int p = beg + t; p < end; p += 256) atomicAdd(&h[ebuf[p].x & 511], 1);
  __syncthreads();
  s2[t] = h[2 * t] + h[2 * t + 1];
  __syncthreads();
  for (int off = 1; off < 256; off <<= 1) {
    int v = (t >= off) ? s2[t - off] : 0;
    __syncthreads();
    s2[t] += v;
    __syncthreads();
  }
  int ep = (t == 0) ? 0 : s2[t - 1];
  cur[2 * t] = ep;
  cur[2 * t + 1] = ep + h[2 * t];
  int dg = (b << 9) + 2 * t;
  if (dg < N) row_ptr[dg] = beg + cur[2 * t];
  if (dg + 1 < N) row_ptr[dg + 1] = beg + cur[2 * t + 1];
  __syncthreads();
  for (int p = beg + t; p < end; p += 256) {
    int2 e2 = ebuf[p];
    int pos = beg + atomicAdd(&cur[e2.x & 511], 1);
    colb[pos] = e2.y;
  }
}

// =================== weight pre-convert: fp16 MFMA-frag blob (hi only, r15) ===================
__global__ void preconv_kernel(const float* __restrict__ W1_0, const float* __restrict__ W1,
                               const float* __restrict__ W2, const float* __restrict__ Wr1,
                               ushort_t* __restrict__ WB) {
  int g = blockIdx.y;
  int e = blockIdx.x * 256 + threadIdx.x;
  int KP = (g == 0) ? 32 : 128;
  if (e >= KP * 128) return;
  int k = e >> 7, n = e & 127;
  float v;
  if (g == 0) v = (k < 16) ? W1_0[k * 128 + n] : 0.0f;
  else if (g <= 7) v = W1[(size_t)(g - 1) * 16384 + e];
  else if (g <= 15) v = W2[(size_t)(g - 8) * 16384 + e];
  else v = Wr1[e];
  size_t base = (g == 0) ? 0 : (8192 + (size_t)(g - 1) * 32768);
  int unit = ((k >> 5) << 9) + ((n >> 4) << 6) + (n & 15) + (((k >> 3) & 3) << 4);
  WB[base + (size_t)unit * 8 + (k & 7)] = __builtin_bit_cast(ushort_t, (_Float16)v);
}

// ============================ layer-0 aggregation (F=16, fp32) ============================
__global__ __launch_bounds__(256) void agg16_kernel(
    const float* __restrict__ X, const int* __restrict__ rp, const int* __restrict__ colb,
    const float* __restrict__ eps, float* __restrict__ Z, int N) {
  int g = threadIdx.x >> 3;
  int l = threadIdx.x & 7;
  int n = blockIdx.x * 32 + g;
  if (n >= N) return;
  float e = 1.0f + eps[0];
  const float2* X2 = (const float2*)X;
  float2 self = X2[(size_t)n * 8 + l];
  float2 acc = make_float2(self.x * e, self.y * e);
  float2 acc2 = make_float2(0.0f, 0.0f);
  int beg = rp[n], end = rp[n + 1];
  int p = beg;
  for (; p + 4 <= end; p += 4) {
    int s0 = colb[p], s1 = colb[p + 1], s2 = colb[p + 2], s3 = colb[p + 3];
    float2 v0 = X2[(size_t)s0 * 8 + l];
    float2 v1 = X2[(size_t)s1 * 8 + l];
    float2 v2 = X2[(size_t)s2 * 8 + l];
    float2 v3 = X2[(size_t)s3 * 8 + l];
    acc.x += v0.x; acc.y += v0.y;
    acc2.x += v1.x; acc2.y += v1.y;
    acc.x += v2.x; acc.y += v2.y;
    acc2.x += v3.x; acc2.y += v3.y;
  }
  for (; p < end; ++p) {
    int s = colb[p];
    float2 v = X2[(size_t)s * 8 + l];
    acc.x += v.x; acc.y += v.y;
  }
  acc.x += acc2.x; acc.y += acc2.y;
  ((float2*)Z)[(size_t)n * 8 + l] = acc;
}

// layers 1..7 aggregation — r17: split-wave gather. Two 32-lane halves each gather a
// DIFFERENT edge with uint2 (8 B) loads (32 lanes cover one 256 B row); halves combined
// with one shfl_xor(32) per accumulator. Same bytes + VALU as r9 form, HALF the memory
// instructions -> 2x MLP per issue slot. (r16 grid-barrier fusion: -655 us, reverted.)
// smode: 0 = no skip, 1 = SKIP store (first touch at L=2), 2 = SKIP += (L=4,6).
__global__ __launch_bounds__(256) void agg128_kernel(
    const ushort_t* __restrict__ Y, const float* __restrict__ av, const float* __restrict__ cv,
    const int* __restrict__ rp, const int* __restrict__ colb,
    const float* __restrict__ eps, int layer, uint_t* __restrict__ Z,
    float* __restrict__ SKIP, int smode, int N) {
  int wv = threadIdx.x >> 6;
  int lane = threadIdx.x & 63;
  int half = lane >> 5;
  int l32 = lane & 31;
  int n = blockIdx.x * 4 + wv;
  if (n >= N) return;
  float e = 1.0f + eps[layer];
  float4 a4 = *(const float4*)(av + l32 * 4);
  float4 c4 = *(const float4*)(cv + l32 * 4);
  const uint2* Y2 = (const uint2*)Y;   // row = 32 x uint2 (256 B)
  // self term (both halves read same row; low half owns SKIP + init)
  uint2 sv = Y2[(size_t)n * 32 + l32];
  float h0 = fmaxf(fmaf(a4.x, f16l(sv.x), c4.x), 0.0f);
  float h1 = fmaxf(fmaf(a4.y, f16h(sv.x), c4.y), 0.0f);
  float h2 = fmaxf(fmaf(a4.z, f16l(sv.y), c4.z), 0.0f);
  float h3 = fmaxf(fmaf(a4.w, f16h(sv.y), c4.w), 0.0f);
  if (half == 0) {
    if (smode == 1) {
      ((float4*)SKIP)[(size_t)n * 32 + l32] = make_float4(h0, h1, h2, h3);
    } else if (smode == 2) {
      float4* S4 = (float4*)SKIP;
      float4 s = S4[(size_t)n * 32 + l32];
      s.x += h0; s.y += h1; s.z += h2; s.w += h3;
      S4[(size_t)n * 32 + l32] = s;
    }
  }
  float ax0 = half ? 0.0f : h0 * e;
  float ax1 = half ? 0.0f : h1 * e;
  float ax2 = half ? 0.0f : h2 * e;
  float ax3 = half ? 0.0f : h3 * e;
  float bx0 = 0.0f, bx1 = 0.0f, bx2 = 0.0f, bx3 = 0.0f;
  int beg = rp[n], end = rp[n + 1];
  int p = beg;
  for (; p + 8 <= end; p += 8) {
    int s0 = colb[p + half];
    int s1 = colb[p + 2 + half];
    int s2 = colb[p + 4 + half];
    int s3 = colb[p + 6 + half];
    uint2 v0 = Y2[(size_t)s0 * 32 + l32];
    uint2 v1 = Y2[(size_t)s1 * 32 + l32];
    uint2 v2 = Y2[(size_t)s2 * 32 + l32];
    uint2 v3 = Y2[(size_t)s3 * 32 + l32];
    ax0 += fmaxf(fmaf(a4.x, f16l(v0.x), c4.x), 0.0f);
    ax1 += fmaxf(fmaf(a4.y, f16h(v0.x), c4.y), 0.0f);
    ax2 += fmaxf(fmaf(a4.z, f16l(v0.y), c4.z), 0.0f);
    ax3 += fmaxf(fmaf(a4.w, f16h(v0.y), c4.w), 0.0f);
    bx0 += fmaxf(fmaf(a4.x, f16l(v1.x), c4.x), 0.0f);
    bx1 += fmaxf(fmaf(a4.y, f16h(v1.x), c4.y), 0.0f);
    bx2 += fmaxf(fmaf(a4.z, f16l(v1.y), c4.z), 0.0f);
    bx3 += fmaxf(fmaf(a4.w, f16h(v1.y), c4.w), 0.0f);
    ax0 += fmaxf(fmaf(a4.x, f16l(v2.x), c4.x), 0.0f);
    ax1 += fmaxf(fmaf(a4.y, f16h(v2.x), c4.y), 0.0f);
    ax2 += fmaxf(fmaf(a4.z, f16l(v2.y), c4.z), 0.0f);
    ax3 += fmaxf(fmaf(a4.w, f16h(v2.y), c4.w), 0.0f);
    bx0 += fmaxf(fmaf(a4.x, f16l(v3.x), c4.x), 0.0f);
    bx1 += fmaxf(fmaf(a4.y, f16h(v3.x), c4.y), 0.0f);
    bx2 += fmaxf(fmaf(a4.z, f16l(v3.y), c4.z), 0.0f);
    bx3 += fmaxf(fmaf(a4.w, f16h(v3.y), c4.w), 0.0f);
  }
  for (; p + 2 <= end; p += 2) {
    int s = colb[p + half];
    uint2 v = Y2[(size_t)s * 32 + l32];
    ax0 += fmaxf(fmaf(a4.x, f16l(v.x), c4.x), 0.0f);
    ax1 += fmaxf(fmaf(a4.y, f16h(v.x), c4.y), 0.0f);
    ax2 += fmaxf(fmaf(a4.z, f16l(v.y), c4.z), 0.0f);
    ax3 += fmaxf(fmaf(a4.w, f16h(v.y), c4.w), 0.0f);
  }
  if (p < end && half == 0) {   // odd leftover edge: low half only
    int s = colb[p];
    uint2 v = Y2[(size_t)s * 32 + l32];
    ax0 += fmaxf(fmaf(a4.x, f16l(v.x), c4.x), 0.0f);
    ax1 += fmaxf(fmaf(a4.y, f16h(v.x), c4.y), 0.0f);
    ax2 += fmaxf(fmaf(a4.z, f16l(v.y), c4.z), 0.0f);
    ax3 += fmaxf(fmaf(a4.w, f16h(v.y), c4.w), 0.0f);
  }
  ax0 += bx0; ax1 += bx1; ax2 += bx2; ax3 += bx3;
  ax0 += __shfl_xor(ax0, 32, 64);
  ax1 += __shfl_xor(ax1, 32, 64);
  ax2 += __shfl_xor(ax2, 32, 64);
  ax3 += __shfl_xor(ax3, 32, 64);
  if (half == 0) {
    uint2 o;
    o.x = pk16(ax0, ax1);
    o.y = pk16(ax2, ax3);
    ((uint2*)Z)[(size_t)n * 32 + l32] = o;
  }
}

// ======== LDS-free fp16 MFMA GEMM — r15: single-B (hi-only) ========
// MODE 0: a = A2u fp16 [M][128] direct (nt loads)
// MODE 1: a = relu(pa*x+pc), x = A2u fp16 (plain loads — same-grid producer, L2 reuse)
// MODE 2: a = 0.25*(A fp32 SKIP + relu(pa*y+pc)), y = A2u fp16
// MODE 3: a = (fp16)A, A fp32 [M][16], K=32 pad
// OUT 0: C fp32 (nt)   OUT 1: C fp16 (plain — consumer reuses via cache)
template <int KTOT, int MODE, int OUT>
__global__ __launch_bounds__(256, 4) void gemm_mfma(
    const float* __restrict__ A, const ushort_t* __restrict__ A2u,
    const ushort_t* __restrict__ Bhi,
    const float* __restrict__ bias,
    const float* __restrict__ pa, const float* __restrict__ pc,
    void* __restrict__ Cv,
    float* __restrict__ gsum, float* __restrict__ gsq,
    float* __restrict__ aout, float* __restrict__ cout, int* __restrict__ cnt,
    const float* __restrict__ gamma, const float* __restrict__ beta,
    float invN, int M, int nb) {
  __shared__ float s_part[4][256];   // [wave][0..127]=sum, [128..255]=sumsq
  __shared__ int s_last;
  const int tid = threadIdx.x;
  const int w = tid >> 6;
  const int lane = tid & 63;
  const int ln = lane & 15;
  const int quad = lane >> 4;
  const int brow = blockIdx.x * 128;
  constexpr int AST = (MODE == 3) ? 16 : 128;

  int r0 = brow + (w << 5) + ln;       if (r0 >= M) r0 = M - 1;
  int r1 = brow + (w << 5) + 16 + ln;  if (r1 >= M) r1 = M - 1;

  f32x4 acc[2][8];
#pragma unroll
  for (int rt = 0; rt < 2; ++rt)
#pragma unroll
    for (int ct = 0; ct < 8; ++ct) acc[rt][ct] = (f32x4){0.0f, 0.0f, 0.0f, 0.0f};

  constexpr int KC = KTOT / 32;
#pragma unroll
  for (int kcl = 0; kcl < KC; ++kcl) {
    const int kb = (kcl << 5) + (quad << 3);
    f16x8 af0, af1;
    if constexpr (MODE == 0) {
      af0 = __builtin_bit_cast(f16x8, ntl_s8(A2u + (size_t)r0 * 128 + kb));
      af1 = __builtin_bit_cast(f16x8, ntl_s8(A2u + (size_t)r1 * 128 + kb));
    } else if constexpr (MODE == 1) {
      uint32x4 xa = *(const uint32x4*)(A2u + (size_t)r0 * 128 + kb);
      uint32x4 xb = *(const uint32x4*)(A2u + (size_t)r1 * 128 + kb);
      float4 p0 = *(const float4*)(pa + kb);
      float4 p1 = *(const float4*)(pa + kb + 4);
      float4 q0 = *(const float4*)(pc + kb);
      float4 q1 = *(const float4*)(pc + kb + 4);
      float pp[8] = {p0.x, p0.y, p0.z, p0.w, p1.x, p1.y, p1.z, p1.w};
      float qq[8] = {q0.x, q0.y, q0.z, q0.w, q1.x, q1.y, q1.z, q1.w};
      float e0[8] = {f16l(xa.x), f16h(xa.x), f16l(xa.y), f16h(xa.y),
                     f16l(xa.z), f16h(xa.z), f16l(xa.w), f16h(xa.w)};
      float e1[8] = {f16l(xb.x), f16h(xb.x), f16l(xb.y), f16h(xb.y),
                     f16l(xb.z), f16h(xb.z), f16l(xb.w), f16h(xb.w)};
#pragma unroll
      for (int j = 0; j < 8; ++j) {
        e0[j] = fmaxf(fmaf(pp[j], e0[j], qq[j]), 0.0f);
        e1[j] = fmaxf(fmaf(pp[j], e1[j], qq[j]), 0.0f);
      }
      af0 = pack8(e0);
      af1 = pack8(e1);
    } else if constexpr (MODE == 2) {
      f32x4 a0 = ntl4(A + (size_t)r0 * AST + kb);
      f32x4 a1 = ntl4(A + (size_t)r0 * AST + kb + 4);
      f32x4 b0 = ntl4(A + (size_t)r1 * AST + kb);
      f32x4 b1 = ntl4(A + (size_t)r1 * AST + kb + 4);
      float s0[8] = {a0.x, a0.y, a0.z, a0.w, a1.x, a1.y, a1.z, a1.w};
      float s1[8] = {b0.x, b0.y, b0.z, b0.w, b1.x, b1.y, b1.z, b1.w};
      uint32x4 ya = *(const uint32x4*)(A2u + (size_t)r0 * 128 + kb);
      uint32x4 yb = *(const uint32x4*)(A2u + (size_t)r1 * 128 + kb);
      float4 p0 = *(const float4*)(pa + kb);
      float4 p1 = *(const float4*)(pa + kb + 4);
      float4 q0 = *(const float4*)(pc + kb);
      float4 q1 = *(const float4*)(pc + kb + 4);
      float pp[8] = {p0.x, p0.y, p0.z, p0.w, p1.x, p1.y, p1.z, p1.w};
      float qq[8] = {q0.x, q0.y, q0.z, q0.w, q1.x, q1.y, q1.z, q1.w};
      float y0a[8] = {f16l(ya.x), f16h(ya.x), f16l(ya.y), f16h(ya.y),
                      f16l(ya.z), f16h(ya.z), f16l(ya.w), f16h(ya.w)};
      float y1a[8] = {f16l(yb.x), f16h(yb.x), f16l(yb.y), f16h(yb.y),
                      f16l(yb.z), f16h(yb.z), f16l(yb.w), f16h(yb.w)};
      float e0[8], e1[8];
#pragma unroll
      for (int j = 0; j < 8; ++j) {
        e0[j] = 0.25f * (s0[j] + fmaxf(fmaf(pp[j], y0a[j], qq[j]), 0.0f));
        e1[j] = 0.25f * (s1[j] + fmaxf(fmaf(pp[j], y1a[j], qq[j]), 0.0f));
      }
      af0 = pack8(e0);
      af1 = pack8(e1);
    } else {  // MODE 3
      if (kb < 16) {
        f32x4 a0 = ntl4(A + (size_t)r0 * AST + kb);
        f32x4 a1 = ntl4(A + (size_t)r0 * AST + kb + 4);
        f32x4 b0 = ntl4(A + (size_t)r1 * AST + kb);
        f32x4 b1 = ntl4(A + (size_t)r1 * AST + kb + 4);
        float e0[8] = {a0.x, a0.y, a0.z, a0.w, a1.x, a1.y, a1.z, a1.w};
        float e1[8] = {b0.x, b0.y, b0.z, b0.w, b1.x, b1.y, b1.z, b1.w};
        af0 = pack8(e0);
        af1 = pack8(e1);
      } else {
#pragma unroll
        for (int j = 0; j < 8; ++j) { af0[j] = (_Float16)0.0f; af1[j] = (_Float16)0.0f; }
      }
    }
    const ushort_t* bh_base = Bhi + (((size_t)(kcl << 9) + lane) << 3);
#pragma unroll
    for (int ct = 0; ct < 8; ++ct) {
      f16x8 bh = __builtin_bit_cast(f16x8, *(const short8*)(bh_base + (ct << 9)));
      acc[0][ct] = __builtin_amdgcn_mfma_f32_16x16x32_f16(af0, bh, acc[0][ct], 0, 0, 0);
      acc[1][ct] = __builtin_amdgcn_mfma_f32_16x16x32_f16(af1, bh, acc[1][ct], 0, 0, 0);
    }
  }

  // ---- epilogue: bias, store, quad-shuffle stats ----
#pragma unroll
  for (int ct = 0; ct < 8; ++ct) {
    int col = (ct << 4) + ln;
    float bsc = bias[col];
    float csum = 0.0f, csq = 0.0f;
#pragma unroll
    for (int rt = 0; rt < 2; ++rt) {
#pragma unroll
      for (int i = 0; i < 4; ++i) {
        int row = brow + (w << 5) + (rt << 4) + (quad << 2) + i;
        if (row < M) {
          float y = acc[rt][ct][i] + bsc;
          csum += y; csq += y * y;
          if constexpr (OUT == 0) {
            nts1(y, &((float*)Cv)[(size_t)row * 128 + col]);
          } else {
            ((ushort_t*)Cv)[(size_t)row * 128 + col] = f2h(y);
          }
        }
      }
    }
    csum += __shfl_xor(csum, 16, 64);
    csum += __shfl_xor(csum, 32, 64);
    csq += __shfl_xor(csq, 16, 64);
    csq += __shfl_xor(csq, 32, 64);
    if (quad == 0) {
      s_part[w][col] = csum;
      s_part[w][128 + col] = csq;
    }
  }
  __syncthreads();
  if (tid < 128) {
    float s = s_part[0][tid] + s_part[1][tid] + s_part[2][tid] + s_part[3][tid];
    float q = s_part[0][128 + tid] + s_part[1][128 + tid] +
              s_part[2][128 + tid] + s_part[3][128 + tid];
    atomicAdd(&gsum[tid], s);   // relaxed device-scope, no flush (r6)
    atomicAdd(&gsq[tid], q);
  }
  __syncthreads();   // drains vmcnt -> stats atomics complete
  if (tid == 0) {
    int v = __hip_atomic_fetch_add(cnt, 1, __ATOMIC_RELAXED, __HIP_MEMORY_SCOPE_AGENT);
    s_last = (v == nb - 1) ? 1 : 0;
  }
  __syncthreads();
  if (s_last && tid < 128) {
    float s = __hip_atomic_load(&gsum[tid], __ATOMIC_RELAXED, __HIP_MEMORY_SCOPE_AGENT);
    float q = __hip_atomic_load(&gsq[tid], __ATOMIC_RELAXED, __HIP_MEMORY_SCOPE_AGENT);
    float mu = s * invN;
    float var = q * invN - mu * mu;
    float sc = gamma[tid] * rsqrtf(var + BN_EPS);
    aout[tid] = sc;
    cout[tid] = beta[tid] - sc * mu;
  }
}

// ============================ regressor head ============================
__global__ __launch_bounds__(256) void finaldot_kernel(
    const float* __restrict__ Y, const float* __restrict__ a, const float* __restrict__ c,
    const float* __restrict__ Wr2, const float* __restrict__ br2,
    float* __restrict__ out, int N) {
  int wv = threadIdx.x >> 6;
  int lane = threadIdx.x & 63;
  int n = blockIdx.x * 4 + wv;
  if (n >= N) return;
  float2 y = *(const float2*)(Y + (size_t)n * HID + lane * 2);
  int c0 = lane * 2;
  float s = fmaxf(fmaf(a[c0], y.x, c[c0]), 0.0f) * Wr2[c0] +
            fmaxf(fmaf(a[c0 + 1], y.y, c[c0 + 1]), 0.0f) * Wr2[c0 + 1];
  for (int off = 32; off > 0; off >>= 1) s += __shfl_down(s, off, 64);
  if (lane == 0) out[n] = 1.0f / (1.0f + expf(-(s + br2[0])));
}

// ============================ launch ============================
extern "C" void kernel_launch(void* const* d_in, const int* in_sizes, int n_in,
                              void* d_out, int out_size, void* d_ws, size_t ws_size,
                              hipStream_t stream) {
  const float* x     = (const float*)d_in[0];
  const int*   ei    = (const int*)d_in[1];
  const float* eps   = (const float*)d_in[2];
  const float* W1_0  = (const float*)d_in[3];
  const float* b1_0  = (const float*)d_in[4];
  const float* W1    = (const float*)d_in[5];
  const float* b1    = (const float*)d_in[6];
  const float* g_in  = (const float*)d_in[7];
  const float* be_in = (const float*)d_in[8];
  const float* W2    = (const float*)d_in[9];
  const float* b2    = (const float*)d_in[10];
  const float* g_out = (const float*)d_in[11];
  const float* be_out= (const float*)d_in[12];
  const float* Wr1   = (const float*)d_in[13];
  const float* br1   = (const float*)d_in[14];
  const float* gr    = (const float*)d_in[15];
  const float* ber   = (const float*)d_in[16];
  const float* Wr2   = (const float*)d_in[17];
  const float* br2   = (const float*)d_in[18];
  float* out = (float*)d_out;

  const int N = in_sizes[0] / IN_F;   // 100000
  const int E = in_sizes[1] / 2;      // 1600000
  const int* srcv = ei;
  const int* dstv = ei + E;
  const int nbk = (N + 511) >> 9;     // 196 buckets

  // workspace carve (sizes unchanged; X0 region reused as fp16 [N][128] = X0u)
  float* X0    = (float*)d_ws;                  // [N][128] fp32-sized (fp16 Z/H1 + fp32 head)
  float* SKIP  = X0 + (size_t)N * HID;          // [N][128] fp32 (L0 [N,16] temp, then skip)
  ushort_t* YB = (ushort_t*)(SKIP + (size_t)N * HID);  // [N][128] fp16 Y (hot gather target)
  int* colb    = (int*)(YB + (size_t)N * HID);
  int* row_ptr = colb + E;
  int2* ebuf   = (int2*)(row_ptr + (N + 4));
  int* bucketCnt  = (int*)(ebuf + E);
  int* bucketBase = bucketCnt + 256;
  int* bucketCur  = bucketBase + 260;
  float* arena = (float*)(bucketCur + 256);     // 17 slots x 640 floats
  ushort_t* WB = (ushort_t*)(arena + 17 * 640); // hi blob (fp16)
  ushort_t* X0u = (ushort_t*)X0;

  hipMemsetAsync(bucketCnt, 0, sizeof(int) * 256, stream);
  hipMemsetAsync(arena, 0, sizeof(float) * 17 * 640, stream);

  // CSR build (bucket sort)
  int nbE = (E + 2047) / 2048;
  bhist_kernel<<<nbE, 256, 0, stream>>>(dstv, bucketCnt, E, nbk);
  bscan_kernel<<<1, 256, 0, stream>>>(bucketCnt, bucketBase, bucketCur, row_ptr, N, E, nbk);
  bscatter_kernel<<<nbE, 256, 0, stream>>>(srcv, dstv, bucketCur, ebuf, E, nbk);
  bcsr_kernel<<<nbk, 256, 0, stream>>>(ebuf, bucketBase, row_ptr, colb, N);
  preconv_kernel<<<dim3(64, 17), 256, 0, stream>>>(W1_0, W1, W2, Wr1, WB);

  const int gg = (N + 127) / 128;   // 128-row tiles (r10 optimum)
  const float invN = 1.0f / (float)N;
#define SLOT(s) (arena + (s) * 640)
#define SSUM(s) SLOT(s)
#define SSQ(s)  (SLOT(s) + 128)
#define SA(s)   (SLOT(s) + 256)
#define SC(s)   (SLOT(s) + 384)
#define SCNT(s) ((int*)(SLOT(s) + 512))
#define WBH(g)  (WB + ((g) == 0 ? 0 : (8192 + (size_t)((g) - 1) * 32768)))

  // ---- layer 0 ----  agg16: x -> SKIP[N,16] fp32; g0a: SKIP -> X0u fp16; g0b: X0u -> YB fp16
  agg16_kernel<<<(N + 31) / 32, 256, 0, stream>>>(x, row_ptr, colb, eps, SKIP, N);
  gemm_mfma<32, 3, 1><<<gg, 256, 0, stream>>>(
      SKIP, nullptr, WBH(0), b1_0, nullptr, nullptr, X0u,
      SSUM(0), SSQ(0), SA(0), SC(0), SCNT(0), g_in, be_in, invN, N, gg);
  gemm_mfma<128, 1, 1><<<gg, 256, 0, stream>>>(
      nullptr, X0u, WBH(8), b2, SA(0), SC(0), YB,
      SSUM(1), SSQ(1), SA(1), SC(1), SCNT(1), g_out, be_out, invN, N, gg);
  // No SKIP memset: L=2's agg does a plain store (smode=1) covering all N*128 elements.

  // ---- layers 1..7 ----  agg: YB->X0u (fp16 Z); gemm1: X0u->X0u in place; gemm2: X0u->YB
  for (int L = 1; L < NLAYERS; ++L) {
    int sp = 2 * L - 1;
    int s0 = 2 * L, s1 = 2 * L + 1;
    // skip taps h_1,h_3,h_5 at L=2,4,6 (h_7 folded in regressor). First tap stores.
    int smode = ((L - 1) & 1) ? ((L == 2) ? 1 : 2) : 0;
    agg128_kernel<<<(N + 3) / 4, 256, 0, stream>>>(
        YB, SA(sp), SC(sp), row_ptr, colb, eps, L, (uint_t*)X0u, SKIP, smode, N);
    gemm_mfma<128, 0, 1><<<gg, 256, 0, stream>>>(
        nullptr, X0u, WBH(L), b1 + (size_t)(L - 1) * HID, nullptr, nullptr, X0u,
        SSUM(s0), SSQ(s0), SA(s0), SC(s0), SCNT(s0),
        g_in + (size_t)L * HID, be_in + (size_t)L * HID, invN, N, gg);
    gemm_mfma<128, 1, 1><<<gg, 256, 0, stream>>>(
        nullptr, X0u, WBH(8 + L), b2 + (size_t)L * HID, SA(s0), SC(s0), YB,
        SSUM(s1), SSQ(s1), SA(s1), SC(s1), SCNT(s1),
        g_out + (size_t)L * HID, be_out + (size_t)L * HID, invN, N, gg);
  }
  // Y7 in YB (fp16), slot 15 holds its outer-BN params

  // ---- regressor: op = 0.25*(SKIP + relu(a7*Y7+c7)) ----
  gemm_mfma<128, 2, 0><<<gg, 256, 0, stream>>>(
      SKIP, YB, WBH(16), br1, SA(15), SC(15), X0,
      SSUM(16), SSQ(16), SA(16), SC(16), SCNT(16), gr, ber, invN, N, gg);
  finaldot_kernel<<<(N + 3) / 4, 256, 0, stream>>>(X0, SA(16), SC(16), Wr2, br2, out, N);
#undef SLOT
#undef SSUM
#undef SSQ
#undef SA
#undef SC
#undef SCNT
#undef WBH
}

// Round 5
// 1261.141 us; speedup vs baseline: 1.7685x; 1.2078x over previous
//
#include <hip/hip_runtime.h>
#include <hip/hip_bf16.h>

#define NNODES 100000
#define NEDGES 1600000
#define IN_F 16
#define HID 128
#define NLAYERS 8
#define BN_EPS 1e-5f
#define BLOBSZ 532480   // ushorts per blob: 8192 + 16*32768 (hi-only since r15)

typedef __attribute__((ext_vector_type(8))) short short8;
typedef __attribute__((ext_vector_type(8))) _Float16 f16x8;
typedef __attribute__((ext_vector_type(4))) float f32x4;
typedef __attribute__((ext_vector_type(4))) unsigned int uint32x4;
typedef unsigned short ushort_t;
typedef unsigned int uint_t;

// ---- fp16 helpers (r14: whole activation chain fp16) ----
__device__ __forceinline__ float f16l(uint_t u) {
  return (float)__builtin_bit_cast(_Float16, (ushort_t)(u & 0xFFFFu));
}
__device__ __forceinline__ float f16h(uint_t u) {
  return (float)__builtin_bit_cast(_Float16, (ushort_t)(u >> 16));
}
__device__ __forceinline__ ushort_t f2h(float f) {
  return __builtin_bit_cast(ushort_t, (_Float16)f);
}
__device__ __forceinline__ uint_t pk16(float x, float y) {
  return (uint_t)f2h(x) | ((uint_t)f2h(y) << 16);
}
__device__ __forceinline__ f16x8 pack8(const float* v) {
  f16x8 r;
#pragma unroll
  for (int j = 0; j < 8; ++j) r[j] = (_Float16)v[j];
  return r;
}

// nontemporal helpers (streams with no reuse; YB/X0u stay cached for reuse)
__device__ __forceinline__ f32x4 ntl4(const float* p) {
  return __builtin_nontemporal_load((const f32x4*)p);
}
__device__ __forceinline__ short8 ntl_s8(const ushort_t* p) {
  return __builtin_nontemporal_load((const short8*)p);
}
__device__ __forceinline__ void nts1(float v, float* p) {
  __builtin_nontemporal_store(v, p);
}

// ===================== CSR build: 2-level bucket sort (r8 win) =====================
__global__ __launch_bounds__(256) void bhist_kernel(
    const int* __restrict__ dst, int* __restrict__ bucketCnt, int E, int nbk) {
  __shared__ int cnt[256];
  int t = threadIdx.x;
  cnt[t] = 0;
  __syncthreads();
  int base = blockIdx.x * 2048 + t * 8;
#pragma unroll
  for (int j = 0; j < 8; ++j) {
    int i = base + j;
    if (i < E) atomicAdd(&cnt[dst[i] >> 9], 1);
  }
  __syncthreads();
  if (t < nbk && cnt[t]) atomicAdd(&bucketCnt[t], cnt[t]);
}

__global__ void bscan_kernel(const int* __restrict__ bucketCnt, int* __restrict__ bucketBase,
                             int* __restrict__ bucketCur, int* __restrict__ row_ptr,
                             int N, int E, int nbk) {
  __shared__ int s[256];
  int t = threadIdx.x;
  s[t] = (t < nbk) ? bucketCnt[t] : 0;
  __syncthreads();
  for (int off = 1; off < 256; off <<= 1) {
    int v = (t >= off) ? s[t - off] : 0;
    __syncthreads();
    s[t] += v;
    __syncthreads();
  }
  int excl = (t == 0) ? 0 : s[t - 1];
  if (t < nbk) { bucketBase[t] = excl; bucketCur[t] = excl; }
  if (t == nbk) bucketBase[t] = E;
  if (t == 0) row_ptr[N] = E;
}

__global__ __launch_bounds__(256) void bscatter_kernel(
    const int* __restrict__ src, const int* __restrict__ dst,
    int* __restrict__ bucketCur, int2* __restrict__ ebuf, int E, int nbk) {
  __shared__ int cnt[256];
  __shared__ int base_l[256];
  int t = threadIdx.x;
  cnt[t] = 0;
  __syncthreads();
  int base = blockIdx.x * 2048 + t * 8;
  int bj[8], lr[8], dj[8], sj[8];
#pragma unroll
  for (int j = 0; j < 8; ++j) {
    int i = base + j;
    if (i < E) {
      dj[j] = dst[i];
      sj[j] = src[i];
      bj[j] = dj[j] >> 9;
      lr[j] = atomicAdd(&cnt[bj[j]], 1);
    } else bj[j] = -1;
  }
  __syncthreads();
  if (t < nbk) base_l[t] = cnt[t] ? atomicAdd(&bucketCur[t], cnt[t]) : 0;
  __syncthreads();
#pragma unroll
  for (int j = 0; j < 8; ++j)
    if (bj[j] >= 0) ebuf[base_l[bj[j]] + lr[j]] = make_int2(dj[j], sj[j]);
}

__global__ __launch_bounds__(256) void bcsr_kernel(
    const int2* __restrict__ ebuf, const int* __restrict__ bucketBase,
    int* __restrict__ row_ptr, int* __restrict__ colb, int N) {
  __shared__ int h[512];
  __shared__ int cur[512];
  __shared__ int s2[256];
  int b = blockIdx.x, t = threadIdx.x;
  int beg = bucketBase[b], end = bucketBase[b + 1];
  h[t] = 0; h[t + 256] = 0;
  __syncthreads();
  for (int p = beg + t; p < end; p += 256) atomicAdd(&h[ebuf[p].x & 511], 1);
  __syncthreads();
  s2[t] = h[2 * t] + h[2 * t + 1];
  __syncthreads();
  for (int off = 1; off < 256; off <<= 1) {
    int v = (t >= off) ? s2[t - off] : 0;
    __syncthreads();
    s2[t] += v;
    __syncthreads();
  }
  int ep = (t == 0) ? 0 : s2[t - 1];
  cur[2 * t] = ep;
  cur[2 * t + 1] = ep + h[2 * t];
  int dg = (b << 9) + 2 * t;
  if (dg < N) row_ptr[dg] = beg + cur[2 * t];
  if (dg + 1 < N) row_ptr[dg + 1] = beg + cur[2 * t + 1];
  __syncthreads();
  for (int p = beg + t; p < end; p += 256) {
    int2 e2 = ebuf[p];
    int pos = beg + atomicAdd(&cur[e2.x & 511], 1);
    colb[pos] = e2.y;
  }
}

// =================== weight pre-convert: fp16 MFMA-frag blob (hi only, r15) ===================
__global__ void preconv_kernel(const float* __restrict__ W1_0, const float* __restrict__ W1,
                               const float* __restrict__ W2, const float* __restrict__ Wr1,
                               ushort_t* __restrict__ WB) {
  int g = blockIdx.y;
  int e = blockIdx.x * 256 + threadIdx.x;
  int KP = (g == 0) ? 32 : 128;
  if (e >= KP * 128) return;
  int k = e >> 7, n = e & 127;
  float v;
  if (g == 0) v = (k < 16) ? W1_0[k * 128 + n] : 0.0f;
  else if (g <= 7) v = W1[(size_t)(g - 1) * 16384 + e];
  else if (g <= 15) v = W2[(size_t)(g - 8) * 16384 + e];
  else v = Wr1[e];
  size_t base = (g == 0) ? 0 : (8192 + (size_t)(g - 1) * 32768);
  int unit = ((k >> 5) << 9) + ((n >> 4) << 6) + (n & 15) + (((k >> 3) & 3) << 4);
  WB[base + (size_t)unit * 8 + (k & 7)] = __builtin_bit_cast(ushort_t, (_Float16)v);
}

// ============================ layer-0 aggregation (F=16, fp32) ============================
__global__ __launch_bounds__(256) void agg16_kernel(
    const float* __restrict__ X, const int* __restrict__ rp, const int* __restrict__ colb,
    const float* __restrict__ eps, float* __restrict__ Z, int N) {
  int g = threadIdx.x >> 3;
  int l = threadIdx.x & 7;
  int n = blockIdx.x * 32 + g;
  if (n >= N) return;
  float e = 1.0f + eps[0];
  const float2* X2 = (const float2*)X;
  float2 self = X2[(size_t)n * 8 + l];
  float2 acc = make_float2(self.x * e, self.y * e);
  float2 acc2 = make_float2(0.0f, 0.0f);
  int beg = rp[n], end = rp[n + 1];
  int p = beg;
  for (; p + 4 <= end; p += 4) {
    int s0 = colb[p], s1 = colb[p + 1], s2 = colb[p + 2], s3 = colb[p + 3];
    float2 v0 = X2[(size_t)s0 * 8 + l];
    float2 v1 = X2[(size_t)s1 * 8 + l];
    float2 v2 = X2[(size_t)s2 * 8 + l];
    float2 v3 = X2[(size_t)s3 * 8 + l];
    acc.x += v0.x; acc.y += v0.y;
    acc2.x += v1.x; acc2.y += v1.y;
    acc.x += v2.x; acc.y += v2.y;
    acc2.x += v3.x; acc2.y += v3.y;
  }
  for (; p < end; ++p) {
    int s = colb[p];
    float2 v = X2[(size_t)s * 8 + l];
    acc.x += v.x; acc.y += v.y;
  }
  acc.x += acc2.x; acc.y += acc2.y;
  ((float2*)Z)[(size_t)n * 8 + l] = acc;
}

// layers 1..7 aggregation — r17: split-wave gather (87->80 us, confirmed win).
// smode: 0 = no skip, 1 = SKIP store (first touch at L=2), 2 = SKIP += (L=4,6).
__global__ __launch_bounds__(256) void agg128_kernel(
    const ushort_t* __restrict__ Y, const float* __restrict__ av, const float* __restrict__ cv,
    const int* __restrict__ rp, const int* __restrict__ colb,
    const float* __restrict__ eps, int layer, uint_t* __restrict__ Z,
    float* __restrict__ SKIP, int smode, int N) {
  int wv = threadIdx.x >> 6;
  int lane = threadIdx.x & 63;
  int half = lane >> 5;
  int l32 = lane & 31;
  int n = blockIdx.x * 4 + wv;
  if (n >= N) return;
  float e = 1.0f + eps[layer];
  float4 a4 = *(const float4*)(av + l32 * 4);
  float4 c4 = *(const float4*)(cv + l32 * 4);
  const uint2* Y2 = (const uint2*)Y;   // row = 32 x uint2 (256 B)
  // self term (both halves read same row; low half owns SKIP + init)
  uint2 sv = Y2[(size_t)n * 32 + l32];
  float h0 = fmaxf(fmaf(a4.x, f16l(sv.x), c4.x), 0.0f);
  float h1 = fmaxf(fmaf(a4.y, f16h(sv.x), c4.y), 0.0f);
  float h2 = fmaxf(fmaf(a4.z, f16l(sv.y), c4.z), 0.0f);
  float h3 = fmaxf(fmaf(a4.w, f16h(sv.y), c4.w), 0.0f);
  if (half == 0) {
    if (smode == 1) {
      ((float4*)SKIP)[(size_t)n * 32 + l32] = make_float4(h0, h1, h2, h3);
    } else if (smode == 2) {
      float4* S4 = (float4*)SKIP;
      float4 s = S4[(size_t)n * 32 + l32];
      s.x += h0; s.y += h1; s.z += h2; s.w += h3;
      S4[(size_t)n * 32 + l32] = s;
    }
  }
  float ax0 = half ? 0.0f : h0 * e;
  float ax1 = half ? 0.0f : h1 * e;
  float ax2 = half ? 0.0f : h2 * e;
  float ax3 = half ? 0.0f : h3 * e;
  float bx0 = 0.0f, bx1 = 0.0f, bx2 = 0.0f, bx3 = 0.0f;
  int beg = rp[n], end = rp[n + 1];
  int p = beg;
  for (; p + 8 <= end; p += 8) {
    int s0 = colb[p + half];
    int s1 = colb[p + 2 + half];
    int s2 = colb[p + 4 + half];
    int s3 = colb[p + 6 + half];
    uint2 v0 = Y2[(size_t)s0 * 32 + l32];
    uint2 v1 = Y2[(size_t)s1 * 32 + l32];
    uint2 v2 = Y2[(size_t)s2 * 32 + l32];
    uint2 v3 = Y2[(size_t)s3 * 32 + l32];
    ax0 += fmaxf(fmaf(a4.x, f16l(v0.x), c4.x), 0.0f);
    ax1 += fmaxf(fmaf(a4.y, f16h(v0.x), c4.y), 0.0f);
    ax2 += fmaxf(fmaf(a4.z, f16l(v0.y), c4.z), 0.0f);
    ax3 += fmaxf(fmaf(a4.w, f16h(v0.y), c4.w), 0.0f);
    bx0 += fmaxf(fmaf(a4.x, f16l(v1.x), c4.x), 0.0f);
    bx1 += fmaxf(fmaf(a4.y, f16h(v1.x), c4.y), 0.0f);
    bx2 += fmaxf(fmaf(a4.z, f16l(v1.y), c4.z), 0.0f);
    bx3 += fmaxf(fmaf(a4.w, f16h(v1.y), c4.w), 0.0f);
    ax0 += fmaxf(fmaf(a4.x, f16l(v2.x), c4.x), 0.0f);
    ax1 += fmaxf(fmaf(a4.y, f16h(v2.x), c4.y), 0.0f);
    ax2 += fmaxf(fmaf(a4.z, f16l(v2.y), c4.z), 0.0f);
    ax3 += fmaxf(fmaf(a4.w, f16h(v2.y), c4.w), 0.0f);
    bx0 += fmaxf(fmaf(a4.x, f16l(v3.x), c4.x), 0.0f);
    bx1 += fmaxf(fmaf(a4.y, f16h(v3.x), c4.y), 0.0f);
    bx2 += fmaxf(fmaf(a4.z, f16l(v3.y), c4.z), 0.0f);
    bx3 += fmaxf(fmaf(a4.w, f16h(v3.y), c4.w), 0.0f);
  }
  for (; p + 2 <= end; p += 2) {
    int s = colb[p + half];
    uint2 v = Y2[(size_t)s * 32 + l32];
    ax0 += fmaxf(fmaf(a4.x, f16l(v.x), c4.x), 0.0f);
    ax1 += fmaxf(fmaf(a4.y, f16h(v.x), c4.y), 0.0f);
    ax2 += fmaxf(fmaf(a4.z, f16l(v.y), c4.z), 0.0f);
    ax3 += fmaxf(fmaf(a4.w, f16h(v.y), c4.w), 0.0f);
  }
  if (p < end && half == 0) {   // odd leftover edge: low half only
    int s = colb[p];
    uint2 v = Y2[(size_t)s * 32 + l32];
    ax0 += fmaxf(fmaf(a4.x, f16l(v.x), c4.x), 0.0f);
    ax1 += fmaxf(fmaf(a4.y, f16h(v.x), c4.y), 0.0f);
    ax2 += fmaxf(fmaf(a4.z, f16l(v.y), c4.z), 0.0f);
    ax3 += fmaxf(fmaf(a4.w, f16h(v.y), c4.w), 0.0f);
  }
  ax0 += bx0; ax1 += bx1; ax2 += bx2; ax3 += bx3;
  ax0 += __shfl_xor(ax0, 32, 64);
  ax1 += __shfl_xor(ax1, 32, 64);
  ax2 += __shfl_xor(ax2, 32, 64);
  ax3 += __shfl_xor(ax3, 32, 64);
  if (half == 0) {
    uint2 o;
    o.x = pk16(ax0, ax1);
    o.y = pk16(ax2, ax3);
    ((uint2*)Z)[(size_t)n * 32 + l32] = o;
  }
}

// ======== LDS-free fp16 MFMA GEMM — r18: 8-way-split stats atomics ========
// r18 theory: with all 782 blocks co-resident, epilogue stats were 782-deep same-address
// atomic chains (plus a 782-deep cnt chain) — the dominant per-GEMM cost. Split:
// gsum/gsq are [8][128], block adds into slot bid&7 (chain ~98); hierarchical counter
// cnt[0..7] per class + cnt[8] master (chain 98+8). Last block sums the 8 partials.
// MODE 0: a = A2u fp16 [M][128] direct (nt loads)
// MODE 1: a = relu(pa*x+pc), x = A2u fp16 (plain loads)
// MODE 2: a = 0.25*(A fp32 SKIP + relu(pa*y+pc)), y = A2u fp16
// MODE 3: a = (fp16)A, A fp32 [M][16], K=32 pad
// OUT 0: C fp32 (nt)   OUT 1: C fp16 (plain — consumer reuses via cache)
template <int KTOT, int MODE, int OUT>
__global__ __launch_bounds__(256, 4) void gemm_mfma(
    const float* __restrict__ A, const ushort_t* __restrict__ A2u,
    const ushort_t* __restrict__ Bhi,
    const float* __restrict__ bias,
    const float* __restrict__ pa, const float* __restrict__ pc,
    void* __restrict__ Cv,
    float* __restrict__ gsum, float* __restrict__ gsq,
    float* __restrict__ aout, float* __restrict__ cout, int* __restrict__ cnt,
    const float* __restrict__ gamma, const float* __restrict__ beta,
    float invN, int M, int nb) {
  __shared__ float s_part[4][256];   // [wave][0..127]=sum, [128..255]=sumsq
  __shared__ int s_last;
  const int tid = threadIdx.x;
  const int w = tid >> 6;
  const int lane = tid & 63;
  const int ln = lane & 15;
  const int quad = lane >> 4;
  const int brow = blockIdx.x * 128;
  constexpr int AST = (MODE == 3) ? 16 : 128;

  int r0 = brow + (w << 5) + ln;       if (r0 >= M) r0 = M - 1;
  int r1 = brow + (w << 5) + 16 + ln;  if (r1 >= M) r1 = M - 1;

  f32x4 acc[2][8];
#pragma unroll
  for (int rt = 0; rt < 2; ++rt)
#pragma unroll
    for (int ct = 0; ct < 8; ++ct) acc[rt][ct] = (f32x4){0.0f, 0.0f, 0.0f, 0.0f};

  constexpr int KC = KTOT / 32;
#pragma unroll
  for (int kcl = 0; kcl < KC; ++kcl) {
    const int kb = (kcl << 5) + (quad << 3);
    f16x8 af0, af1;
    if constexpr (MODE == 0) {
      af0 = __builtin_bit_cast(f16x8, ntl_s8(A2u + (size_t)r0 * 128 + kb));
      af1 = __builtin_bit_cast(f16x8, ntl_s8(A2u + (size_t)r1 * 128 + kb));
    } else if constexpr (MODE == 1) {
      uint32x4 xa = *(const uint32x4*)(A2u + (size_t)r0 * 128 + kb);
      uint32x4 xb = *(const uint32x4*)(A2u + (size_t)r1 * 128 + kb);
      float4 p0 = *(const float4*)(pa + kb);
      float4 p1 = *(const float4*)(pa + kb + 4);
      float4 q0 = *(const float4*)(pc + kb);
      float4 q1 = *(const float4*)(pc + kb + 4);
      float pp[8] = {p0.x, p0.y, p0.z, p0.w, p1.x, p1.y, p1.z, p1.w};
      float qq[8] = {q0.x, q0.y, q0.z, q0.w, q1.x, q1.y, q1.z, q1.w};
      float e0[8] = {f16l(xa.x), f16h(xa.x), f16l(xa.y), f16h(xa.y),
                     f16l(xa.z), f16h(xa.z), f16l(xa.w), f16h(xa.w)};
      float e1[8] = {f16l(xb.x), f16h(xb.x), f16l(xb.y), f16h(xb.y),
                     f16l(xb.z), f16h(xb.z), f16l(xb.w), f16h(xb.w)};
#pragma unroll
      for (int j = 0; j < 8; ++j) {
        e0[j] = fmaxf(fmaf(pp[j], e0[j], qq[j]), 0.0f);
        e1[j] = fmaxf(fmaf(pp[j], e1[j], qq[j]), 0.0f);
      }
      af0 = pack8(e0);
      af1 = pack8(e1);
    } else if constexpr (MODE == 2) {
      f32x4 a0 = ntl4(A + (size_t)r0 * AST + kb);
      f32x4 a1 = ntl4(A + (size_t)r0 * AST + kb + 4);
      f32x4 b0 = ntl4(A + (size_t)r1 * AST + kb);
      f32x4 b1 = ntl4(A + (size_t)r1 * AST + kb + 4);
      float s0[8] = {a0.x, a0.y, a0.z, a0.w, a1.x, a1.y, a1.z, a1.w};
      float s1[8] = {b0.x, b0.y, b0.z, b0.w, b1.x, b1.y, b1.z, b1.w};
      uint32x4 ya = *(const uint32x4*)(A2u + (size_t)r0 * 128 + kb);
      uint32x4 yb = *(const uint32x4*)(A2u + (size_t)r1 * 128 + kb);
      float4 p0 = *(const float4*)(pa + kb);
      float4 p1 = *(const float4*)(pa + kb + 4);
      float4 q0 = *(const float4*)(pc + kb);
      float4 q1 = *(const float4*)(pc + kb + 4);
      float pp[8] = {p0.x, p0.y, p0.z, p0.w, p1.x, p1.y, p1.z, p1.w};
      float qq[8] = {q0.x, q0.y, q0.z, q0.w, q1.x, q1.y, q1.z, q1.w};
      float y0a[8] = {f16l(ya.x), f16h(ya.x), f16l(ya.y), f16h(ya.y),
                      f16l(ya.z), f16h(ya.z), f16l(ya.w), f16h(ya.w)};
      float y1a[8] = {f16l(yb.x), f16h(yb.x), f16l(yb.y), f16h(yb.y),
                      f16l(yb.z), f16h(yb.z), f16l(yb.w), f16h(yb.w)};
      float e0[8], e1[8];
#pragma unroll
      for (int j = 0; j < 8; ++j) {
        e0[j] = 0.25f * (s0[j] + fmaxf(fmaf(pp[j], y0a[j], qq[j]), 0.0f));
        e1[j] = 0.25f * (s1[j] + fmaxf(fmaf(pp[j], y1a[j], qq[j]), 0.0f));
      }
      af0 = pack8(e0);
      af1 = pack8(e1);
    } else {  // MODE 3
      if (kb < 16) {
        f32x4 a0 = ntl4(A + (size_t)r0 * AST + kb);
        f32x4 a1 = ntl4(A + (size_t)r0 * AST + kb + 4);
        f32x4 b0 = ntl4(A + (size_t)r1 * AST + kb);
        f32x4 b1 = ntl4(A + (size_t)r1 * AST + kb + 4);
        float e0[8] = {a0.x, a0.y, a0.z, a0.w, a1.x, a1.y, a1.z, a1.w};
        float e1[8] = {b0.x, b0.y, b0.z, b0.w, b1.x, b1.y, b1.z, b1.w};
        af0 = pack8(e0);
        af1 = pack8(e1);
      } else {
#pragma unroll
        for (int j = 0; j < 8; ++j) { af0[j] = (_Float16)0.0f; af1[j] = (_Float16)0.0f; }
      }
    }
    const ushort_t* bh_base = Bhi + (((size_t)(kcl << 9) + lane) << 3);
#pragma unroll
    for (int ct = 0; ct < 8; ++ct) {
      f16x8 bh = __builtin_bit_cast(f16x8, *(const short8*)(bh_base + (ct << 9)));
      acc[0][ct] = __builtin_amdgcn_mfma_f32_16x16x32_f16(af0, bh, acc[0][ct], 0, 0, 0);
      acc[1][ct] = __builtin_amdgcn_mfma_f32_16x16x32_f16(af1, bh, acc[1][ct], 0, 0, 0);
    }
  }

  // ---- epilogue: bias, store, quad-shuffle stats ----
#pragma unroll
  for (int ct = 0; ct < 8; ++ct) {
    int col = (ct << 4) + ln;
    float bsc = bias[col];
    float csum = 0.0f, csq = 0.0f;
#pragma unroll
    for (int rt = 0; rt < 2; ++rt) {
#pragma unroll
      for (int i = 0; i < 4; ++i) {
        int row = brow + (w << 5) + (rt << 4) + (quad << 2) + i;
        if (row < M) {
          float y = acc[rt][ct][i] + bsc;
          csum += y; csq += y * y;
          if constexpr (OUT == 0) {
            nts1(y, &((float*)Cv)[(size_t)row * 128 + col]);
          } else {
            ((ushort_t*)Cv)[(size_t)row * 128 + col] = f2h(y);
          }
        }
      }
    }
    csum += __shfl_xor(csum, 16, 64);
    csum += __shfl_xor(csum, 32, 64);
    csq += __shfl_xor(csq, 16, 64);
    csq += __shfl_xor(csq, 32, 64);
    if (quad == 0) {
      s_part[w][col] = csum;
      s_part[w][128 + col] = csq;
    }
  }
  __syncthreads();
  const int cls = (int)(blockIdx.x & 7);
  if (tid < 128) {
    float s = s_part[0][tid] + s_part[1][tid] + s_part[2][tid] + s_part[3][tid];
    float q = s_part[0][128 + tid] + s_part[1][128 + tid] +
              s_part[2][128 + tid] + s_part[3][128 + tid];
    atomicAdd(&gsum[(cls << 7) + tid], s);   // relaxed device-scope; chain ~nb/8
    atomicAdd(&gsq[(cls << 7) + tid], q);
  }
  __syncthreads();   // drains vmcnt -> stats atomics complete
  if (tid == 0) {
    s_last = 0;
    int clsCnt = (nb >> 3) + ((cls < (nb & 7)) ? 1 : 0);
    int v = __hip_atomic_fetch_add(&cnt[cls], 1, __ATOMIC_RELAXED, __HIP_MEMORY_SCOPE_AGENT);
    if (v == clsCnt - 1) {   // last of this class -> bump master
      int vm = __hip_atomic_fetch_add(&cnt[8], 1, __ATOMIC_RELAXED, __HIP_MEMORY_SCOPE_AGENT);
      if (vm == 7) s_last = 1;
    }
  }
  __syncthreads();
  if (s_last && tid < 128) {
    float s = 0.0f, q = 0.0f;
#pragma unroll
    for (int c = 0; c < 8; ++c) {
      s += __hip_atomic_load(&gsum[(c << 7) + tid], __ATOMIC_RELAXED, __HIP_MEMORY_SCOPE_AGENT);
      q += __hip_atomic_load(&gsq[(c << 7) + tid], __ATOMIC_RELAXED, __HIP_MEMORY_SCOPE_AGENT);
    }
    float mu = s * invN;
    float var = q * invN - mu * mu;
    float sc = gamma[tid] * rsqrtf(var + BN_EPS);
    aout[tid] = sc;
    cout[tid] = beta[tid] - sc * mu;
  }
}

// ============================ regressor head ============================
__global__ __launch_bounds__(256) void finaldot_kernel(
    const float* __restrict__ Y, const float* __restrict__ a, const float* __restrict__ c,
    const float* __restrict__ Wr2, const float* __restrict__ br2,
    float* __restrict__ out, int N) {
  int wv = threadIdx.x >> 6;
  int lane = threadIdx.x & 63;
  int n = blockIdx.x * 4 + wv;
  if (n >= N) return;
  float2 y = *(const float2*)(Y + (size_t)n * HID + lane * 2);
  int c0 = lane * 2;
  float s = fmaxf(fmaf(a[c0], y.x, c[c0]), 0.0f) * Wr2[c0] +
            fmaxf(fmaf(a[c0 + 1], y.y, c[c0 + 1]), 0.0f) * Wr2[c0 + 1];
  for (int off = 32; off > 0; off >>= 1) s += __shfl_down(s, off, 64);
  if (lane == 0) out[n] = 1.0f / (1.0f + expf(-(s + br2[0])));
}

// ============================ launch ============================
extern "C" void kernel_launch(void* const* d_in, const int* in_sizes, int n_in,
                              void* d_out, int out_size, void* d_ws, size_t ws_size,
                              hipStream_t stream) {
  const float* x     = (const float*)d_in[0];
  const int*   ei    = (const int*)d_in[1];
  const float* eps   = (const float*)d_in[2];
  const float* W1_0  = (const float*)d_in[3];
  const float* b1_0  = (const float*)d_in[4];
  const float* W1    = (const float*)d_in[5];
  const float* b1    = (const float*)d_in[6];
  const float* g_in  = (const float*)d_in[7];
  const float* be_in = (const float*)d_in[8];
  const float* W2    = (const float*)d_in[9];
  const float* b2    = (const float*)d_in[10];
  const float* g_out = (const float*)d_in[11];
  const float* be_out= (const float*)d_in[12];
  const float* Wr1   = (const float*)d_in[13];
  const float* br1   = (const float*)d_in[14];
  const float* gr    = (const float*)d_in[15];
  const float* ber   = (const float*)d_in[16];
  const float* Wr2   = (const float*)d_in[17];
  const float* br2   = (const float*)d_in[18];
  float* out = (float*)d_out;

  const int N = in_sizes[0] / IN_F;   // 100000
  const int E = in_sizes[1] / 2;      // 1600000
  const int* srcv = ei;
  const int* dstv = ei + E;
  const int nbk = (N + 511) >> 9;     // 196 buckets

  // workspace carve (arena slots widened for 8-way split stats, r18)
  float* X0    = (float*)d_ws;                  // [N][128] fp32-sized (fp16 Z/H1 + fp32 head)
  float* SKIP  = X0 + (size_t)N * HID;          // [N][128] fp32 (L0 [N,16] temp, then skip)
  ushort_t* YB = (ushort_t*)(SKIP + (size_t)N * HID);  // [N][128] fp16 Y (hot gather target)
  int* colb    = (int*)(YB + (size_t)N * HID);
  int* row_ptr = colb + E;
  int2* ebuf   = (int2*)(row_ptr + (N + 4));
  int* bucketCnt  = (int*)(ebuf + E);
  int* bucketBase = bucketCnt + 256;
  int* bucketCur  = bucketBase + 260;
  // arena: 17 slots x 2368 floats:
  //   [0..1023] gsum8[8][128] | [1024..2047] gsq8[8][128] | [2048..2175] SA
  //   [2176..2303] SC | [2304..2312] cnt8[8]+master | pad
  float* arena = (float*)(bucketCur + 256);
  ushort_t* WB = (ushort_t*)(arena + 17 * 2368); // hi blob (fp16)
  ushort_t* X0u = (ushort_t*)X0;

  hipMemsetAsync(bucketCnt, 0, sizeof(int) * 256, stream);
  hipMemsetAsync(arena, 0, sizeof(float) * 17 * 2368, stream);

  // CSR build (bucket sort)
  int nbE = (E + 2047) / 2048;
  bhist_kernel<<<nbE, 256, 0, stream>>>(dstv, bucketCnt, E, nbk);
  bscan_kernel<<<1, 256, 0, stream>>>(bucketCnt, bucketBase, bucketCur, row_ptr, N, E, nbk);
  bscatter_kernel<<<nbE, 256, 0, stream>>>(srcv, dstv, bucketCur, ebuf, E, nbk);
  bcsr_kernel<<<nbk, 256, 0, stream>>>(ebuf, bucketBase, row_ptr, colb, N);
  preconv_kernel<<<dim3(64, 17), 256, 0, stream>>>(W1_0, W1, W2, Wr1, WB);

  const int gg = (N + 127) / 128;   // 128-row tiles (r10 optimum)
  const float invN = 1.0f / (float)N;
#define SLOT(s) (arena + (s) * 2368)
#define SSUM(s) SLOT(s)
#define SSQ(s)  (SLOT(s) + 1024)
#define SA(s)   (SLOT(s) + 2048)
#define SC(s)   (SLOT(s) + 2176)
#define SCNT(s) ((int*)(SLOT(s) + 2304))
#define WBH(g)  (WB + ((g) == 0 ? 0 : (8192 + (size_t)((g) - 1) * 32768)))

  // ---- layer 0 ----  agg16: x -> SKIP[N,16] fp32; g0a: SKIP -> X0u fp16; g0b: X0u -> YB fp16
  agg16_kernel<<<(N + 31) / 32, 256, 0, stream>>>(x, row_ptr, colb, eps, SKIP, N);
  gemm_mfma<32, 3, 1><<<gg, 256, 0, stream>>>(
      SKIP, nullptr, WBH(0), b1_0, nullptr, nullptr, X0u,
      SSUM(0), SSQ(0), SA(0), SC(0), SCNT(0), g_in, be_in, invN, N, gg);
  gemm_mfma<128, 1, 1><<<gg, 256, 0, stream>>>(
      nullptr, X0u, WBH(8), b2, SA(0), SC(0), YB,
      SSUM(1), SSQ(1), SA(1), SC(1), SCNT(1), g_out, be_out, invN, N, gg);
  // No SKIP memset: L=2's agg does a plain store (smode=1) covering all N*128 elements.

  // ---- layers 1..7 ----  agg: YB->X0u (fp16 Z); gemm1: X0u->X0u in place; gemm2: X0u->YB
  for (int L = 1; L < NLAYERS; ++L) {
    int sp = 2 * L - 1;
    int s0 = 2 * L, s1 = 2 * L + 1;
    // skip taps h_1,h_3,h_5 at L=2,4,6 (h_7 folded in regressor). First tap stores.
    int smode = ((L - 1) & 1) ? ((L == 2) ? 1 : 2) : 0;
    agg128_kernel<<<(N + 3) / 4, 256, 0, stream>>>(
        YB, SA(sp), SC(sp), row_ptr, colb, eps, L, (uint_t*)X0u, SKIP, smode, N);
    gemm_mfma<128, 0, 1><<<gg, 256, 0, stream>>>(
        nullptr, X0u, WBH(L), b1 + (size_t)(L - 1) * HID, nullptr, nullptr, X0u,
        SSUM(s0), SSQ(s0), SA(s0), SC(s0), SCNT(s0),
        g_in + (size_t)L * HID, be_in + (size_t)L * HID, invN, N, gg);
    gemm_mfma<128, 1, 1><<<gg, 256, 0, stream>>>(
        nullptr, X0u, WBH(8 + L), b2 + (size_t)L * HID, SA(s0), SC(s0), YB,
        SSUM(s1), SSQ(s1), SA(s1), SC(s1), SCNT(s1),
        g_out + (size_t)L * HID, be_out + (size_t)L * HID, invN, N, gg);
  }
  // Y7 in YB (fp16), slot 15 holds its outer-BN params

  // ---- regressor: op = 0.25*(SKIP + relu(a7*Y7+c7)) ----
  gemm_mfma<128, 2, 0><<<gg, 256, 0, stream>>>(
      SKIP, YB, WBH(16), br1, SA(15), SC(15), X0,
      SSUM(16), SSQ(16), SA(16), SC(16), SCNT(16), gr, ber, invN, N, gg);
  finaldot_kernel<<<(N + 3) / 4, 256, 0, stream>>>(X0, SA(16), SC(16), Wr2, br2, out, N);
#undef SLOT
#undef SSUM
#undef SSQ
#undef SA
#undef SC
#undef SCNT
#undef WBH
}

// Round 6
// 1180.498 us; speedup vs baseline: 1.8893x; 1.0683x over previous
//
#include <hip/hip_runtime.h>
#include <hip/hip_bf16.h>

#define NNODES 100000
#define NEDGES 1600000
#define IN_F 16
#define HID 128
#define NLAYERS 8
#define BN_EPS 1e-5f
#define BLOBSZ 532480   // ushorts per blob: 8192 + 16*32768 (hi-only since r15)
#define NCLS 32         // r19: 32-way split stats (r18 was 8)

typedef __attribute__((ext_vector_type(8))) short short8;
typedef __attribute__((ext_vector_type(8))) _Float16 f16x8;
typedef __attribute__((ext_vector_type(4))) float f32x4;
typedef __attribute__((ext_vector_type(4))) unsigned int uint32x4;
typedef unsigned short ushort_t;
typedef unsigned int uint_t;

// ---- fp16 helpers (r14: whole activation chain fp16) ----
__device__ __forceinline__ float f16l(uint_t u) {
  return (float)__builtin_bit_cast(_Float16, (ushort_t)(u & 0xFFFFu));
}
__device__ __forceinline__ float f16h(uint_t u) {
  return (float)__builtin_bit_cast(_Float16, (ushort_t)(u >> 16));
}
__device__ __forceinline__ ushort_t f2h(float f) {
  return __builtin_bit_cast(ushort_t, (_Float16)f);
}
__device__ __forceinline__ uint_t pk16(float x, float y) {
  return (uint_t)f2h(x) | ((uint_t)f2h(y) << 16);
}
__device__ __forceinline__ f16x8 pack8(const float* v) {
  f16x8 r;
#pragma unroll
  for (int j = 0; j < 8; ++j) r[j] = (_Float16)v[j];
  return r;
}

// nontemporal helpers (streams with no reuse; YB/X0u stay cached for reuse)
__device__ __forceinline__ f32x4 ntl4(const float* p) {
  return __builtin_nontemporal_load((const f32x4*)p);
}
__device__ __forceinline__ short8 ntl_s8(const ushort_t* p) {
  return __builtin_nontemporal_load((const short8*)p);
}

// ===================== CSR build: 2-level bucket sort (r8 win) =====================
__global__ __launch_bounds__(256) void bhist_kernel(
    const int* __restrict__ dst, int* __restrict__ bucketCnt, int E, int nbk) {
  __shared__ int cnt[256];
  int t = threadIdx.x;
  cnt[t] = 0;
  __syncthreads();
  int base = blockIdx.x * 2048 + t * 8;
#pragma unroll
  for (int j = 0; j < 8; ++j) {
    int i = base + j;
    if (i < E) atomicAdd(&cnt[dst[i] >> 9], 1);
  }
  __syncthreads();
  if (t < nbk && cnt[t]) atomicAdd(&bucketCnt[t], cnt[t]);
}

__global__ void bscan_kernel(const int* __restrict__ bucketCnt, int* __restrict__ bucketBase,
                             int* __restrict__ bucketCur, int* __restrict__ row_ptr,
                             int N, int E, int nbk) {
  __shared__ int s[256];
  int t = threadIdx.x;
  s[t] = (t < nbk) ? bucketCnt[t] : 0;
  __syncthreads();
  for (int off = 1; off < 256; off <<= 1) {
    int v = (t >= off) ? s[t - off] : 0;
    __syncthreads();
    s[t] += v;
    __syncthreads();
  }
  int excl = (t == 0) ? 0 : s[t - 1];
  if (t < nbk) { bucketBase[t] = excl; bucketCur[t] = excl; }
  if (t == nbk) bucketBase[t] = E;
  if (t == 0) row_ptr[N] = E;
}

__global__ __launch_bounds__(256) void bscatter_kernel(
    const int* __restrict__ src, const int* __restrict__ dst,
    int* __restrict__ bucketCur, int2* __restrict__ ebuf, int E, int nbk) {
  __shared__ int cnt[256];
  __shared__ int base_l[256];
  int t = threadIdx.x;
  cnt[t] = 0;
  __syncthreads();
  int base = blockIdx.x * 2048 + t * 8;
  int bj[8], lr[8], dj[8], sj[8];
#pragma unroll
  for (int j = 0; j < 8; ++j) {
    int i = base + j;
    if (i < E) {
      dj[j] = dst[i];
      sj[j] = src[i];
      bj[j] = dj[j] >> 9;
      lr[j] = atomicAdd(&cnt[bj[j]], 1);
    } else bj[j] = -1;
  }
  __syncthreads();
  if (t < nbk) base_l[t] = cnt[t] ? atomicAdd(&bucketCur[t], cnt[t]) : 0;
  __syncthreads();
#pragma unroll
  for (int j = 0; j < 8; ++j)
    if (bj[j] >= 0) ebuf[base_l[bj[j]] + lr[j]] = make_int2(dj[j], sj[j]);
}

__global__ __launch_bounds__(256) void bcsr_kernel(
    const int2* __restrict__ ebuf, const int* __restrict__ bucketBase,
    int* __restrict__ row_ptr, int* __restrict__ colb, int N) {
  __shared__ int h[512];
  __shared__ int cur[512];
  __shared__ int s2[256];
  int b = blockIdx.x, t = threadIdx.x;
  int beg = bucketBase[b], end = bucketBase[b + 1];
  h[t] = 0; h[t + 256] = 0;
  __syncthreads();
  for (int p = beg + t; p < end; p += 256) atomicAdd(&h[ebuf[p].x & 511], 1);
  __syncthreads();
  s2[t] = h[2 * t] + h[2 * t + 1];
  __syncthreads();
  for (int off = 1; off < 256; off <<= 1) {
    int v = (t >= off) ? s2[t - off] : 0;
    __syncthreads();
    s2[t] += v;
    __syncthreads();
  }
  int ep = (t == 0) ? 0 : s2[t - 1];
  cur[2 * t] = ep;
  cur[2 * t + 1] = ep + h[2 * t];
  int dg = (b << 9) + 2 * t;
  if (dg < N) row_ptr[dg] = beg + cur[2 * t];
  if (dg + 1 < N) row_ptr[dg + 1] = beg + cur[2 * t + 1];
  __syncthreads();
  for (int p = beg + t; p < end; p += 256) {
    int2 e2 = ebuf[p];
    int pos = beg + atomicAdd(&cur[e2.x & 511], 1);
    colb[pos] = e2.y;
  }
}

// =================== weight pre-convert: fp16 MFMA-frag blob (hi only, r15) ===================
__global__ void preconv_kernel(const float* __restrict__ W1_0, const float* __restrict__ W1,
                               const float* __restrict__ W2, const float* __restrict__ Wr1,
                               ushort_t* __restrict__ WB) {
  int g = blockIdx.y;
  int e = blockIdx.x * 256 + threadIdx.x;
  int KP = (g == 0) ? 32 : 128;
  if (e >= KP * 128) return;
  int k = e >> 7, n = e & 127;
  float v;
  if (g == 0) v = (k < 16) ? W1_0[k * 128 + n] : 0.0f;
  else if (g <= 7) v = W1[(size_t)(g - 1) * 16384 + e];
  else if (g <= 15) v = W2[(size_t)(g - 8) * 16384 + e];
  else v = Wr1[e];
  size_t base = (g == 0) ? 0 : (8192 + (size_t)(g - 1) * 32768);
  int unit = ((k >> 5) << 9) + ((n >> 4) << 6) + (n & 15) + (((k >> 3) & 3) << 4);
  WB[base + (size_t)unit * 8 + (k & 7)] = __builtin_bit_cast(ushort_t, (_Float16)v);
}

// ============================ layer-0 aggregation (F=16, fp32) ============================
__global__ __launch_bounds__(256) void agg16_kernel(
    const float* __restrict__ X, const int* __restrict__ rp, const int* __restrict__ colb,
    const float* __restrict__ eps, float* __restrict__ Z, int N) {
  int g = threadIdx.x >> 3;
  int l = threadIdx.x & 7;
  int n = blockIdx.x * 32 + g;
  if (n >= N) return;
  float e = 1.0f + eps[0];
  const float2* X2 = (const float2*)X;
  float2 self = X2[(size_t)n * 8 + l];
  float2 acc = make_float2(self.x * e, self.y * e);
  float2 acc2 = make_float2(0.0f, 0.0f);
  int beg = rp[n], end = rp[n + 1];
  int p = beg;
  for (; p + 4 <= end; p += 4) {
    int s0 = colb[p], s1 = colb[p + 1], s2 = colb[p + 2], s3 = colb[p + 3];
    float2 v0 = X2[(size_t)s0 * 8 + l];
    float2 v1 = X2[(size_t)s1 * 8 + l];
    float2 v2 = X2[(size_t)s2 * 8 + l];
    float2 v3 = X2[(size_t)s3 * 8 + l];
    acc.x += v0.x; acc.y += v0.y;
    acc2.x += v1.x; acc2.y += v1.y;
    acc.x += v2.x; acc.y += v2.y;
    acc2.x += v3.x; acc2.y += v3.y;
  }
  for (; p < end; ++p) {
    int s = colb[p];
    float2 v = X2[(size_t)s * 8 + l];
    acc.x += v.x; acc.y += v.y;
  }
  acc.x += acc2.x; acc.y += acc2.y;
  ((float2*)Z)[(size_t)n * 8 + l] = acc;
}

// layers 1..7 aggregation — r17: split-wave gather (87->80 us, confirmed win).
// smode: 0 = no skip, 1 = SKIP store (first touch at L=2), 2 = SKIP += (L=4,6).
__global__ __launch_bounds__(256) void agg128_kernel(
    const ushort_t* __restrict__ Y, const float* __restrict__ av, const float* __restrict__ cv,
    const int* __restrict__ rp, const int* __restrict__ colb,
    const float* __restrict__ eps, int layer, uint_t* __restrict__ Z,
    float* __restrict__ SKIP, int smode, int N) {
  int wv = threadIdx.x >> 6;
  int lane = threadIdx.x & 63;
  int half = lane >> 5;
  int l32 = lane & 31;
  int n = blockIdx.x * 4 + wv;
  if (n >= N) return;
  float e = 1.0f + eps[layer];
  float4 a4 = *(const float4*)(av + l32 * 4);
  float4 c4 = *(const float4*)(cv + l32 * 4);
  const uint2* Y2 = (const uint2*)Y;   // row = 32 x uint2 (256 B)
  // self term (both halves read same row; low half owns SKIP + init)
  uint2 sv = Y2[(size_t)n * 32 + l32];
  float h0 = fmaxf(fmaf(a4.x, f16l(sv.x), c4.x), 0.0f);
  float h1 = fmaxf(fmaf(a4.y, f16h(sv.x), c4.y), 0.0f);
  float h2 = fmaxf(fmaf(a4.z, f16l(sv.y), c4.z), 0.0f);
  float h3 = fmaxf(fmaf(a4.w, f16h(sv.y), c4.w), 0.0f);
  if (half == 0) {
    if (smode == 1) {
      ((float4*)SKIP)[(size_t)n * 32 + l32] = make_float4(h0, h1, h2, h3);
    } else if (smode == 2) {
      float4* S4 = (float4*)SKIP;
      float4 s = S4[(size_t)n * 32 + l32];
      s.x += h0; s.y += h1; s.z += h2; s.w += h3;
      S4[(size_t)n * 32 + l32] = s;
    }
  }
  float ax0 = half ? 0.0f : h0 * e;
  float ax1 = half ? 0.0f : h1 * e;
  float ax2 = half ? 0.0f : h2 * e;
  float ax3 = half ? 0.0f : h3 * e;
  float bx0 = 0.0f, bx1 = 0.0f, bx2 = 0.0f, bx3 = 0.0f;
  int beg = rp[n], end = rp[n + 1];
  int p = beg;
  for (; p + 8 <= end; p += 8) {
    int s0 = colb[p + half];
    int s1 = colb[p + 2 + half];
    int s2 = colb[p + 4 + half];
    int s3 = colb[p + 6 + half];
    uint2 v0 = Y2[(size_t)s0 * 32 + l32];
    uint2 v1 = Y2[(size_t)s1 * 32 + l32];
    uint2 v2 = Y2[(size_t)s2 * 32 + l32];
    uint2 v3 = Y2[(size_t)s3 * 32 + l32];
    ax0 += fmaxf(fmaf(a4.x, f16l(v0.x), c4.x), 0.0f);
    ax1 += fmaxf(fmaf(a4.y, f16h(v0.x), c4.y), 0.0f);
    ax2 += fmaxf(fmaf(a4.z, f16l(v0.y), c4.z), 0.0f);
    ax3 += fmaxf(fmaf(a4.w, f16h(v0.y), c4.w), 0.0f);
    bx0 += fmaxf(fmaf(a4.x, f16l(v1.x), c4.x), 0.0f);
    bx1 += fmaxf(fmaf(a4.y, f16h(v1.x), c4.y), 0.0f);
    bx2 += fmaxf(fmaf(a4.z, f16l(v1.y), c4.z), 0.0f);
    bx3 += fmaxf(fmaf(a4.w, f16h(v1.y), c4.w), 0.0f);
    ax0 += fmaxf(fmaf(a4.x, f16l(v2.x), c4.x), 0.0f);
    ax1 += fmaxf(fmaf(a4.y, f16h(v2.x), c4.y), 0.0f);
    ax2 += fmaxf(fmaf(a4.z, f16l(v2.y), c4.z), 0.0f);
    ax3 += fmaxf(fmaf(a4.w, f16h(v2.y), c4.w), 0.0f);
    bx0 += fmaxf(fmaf(a4.x, f16l(v3.x), c4.x), 0.0f);
    bx1 += fmaxf(fmaf(a4.y, f16h(v3.x), c4.y), 0.0f);
    bx2 += fmaxf(fmaf(a4.z, f16l(v3.y), c4.z), 0.0f);
    bx3 += fmaxf(fmaf(a4.w, f16h(v3.y), c4.w), 0.0f);
  }
  for (; p + 2 <= end; p += 2) {
    int s = colb[p + half];
    uint2 v = Y2[(size_t)s * 32 + l32];
    ax0 += fmaxf(fmaf(a4.x, f16l(v.x), c4.x), 0.0f);
    ax1 += fmaxf(fmaf(a4.y, f16h(v.x), c4.y), 0.0f);
    ax2 += fmaxf(fmaf(a4.z, f16l(v.y), c4.z), 0.0f);
    ax3 += fmaxf(fmaf(a4.w, f16h(v.y), c4.w), 0.0f);
  }
  if (p < end && half == 0) {   // odd leftover edge: low half only
    int s = colb[p];
    uint2 v = Y2[(size_t)s * 32 + l32];
    ax0 += fmaxf(fmaf(a4.x, f16l(v.x), c4.x), 0.0f);
    ax1 += fmaxf(fmaf(a4.y, f16h(v.x), c4.y), 0.0f);
    ax2 += fmaxf(fmaf(a4.z, f16l(v.y), c4.z), 0.0f);
    ax3 += fmaxf(fmaf(a4.w, f16h(v.y), c4.w), 0.0f);
  }
  ax0 += bx0; ax1 += bx1; ax2 += bx2; ax3 += bx3;
  ax0 += __shfl_xor(ax0, 32, 64);
  ax1 += __shfl_xor(ax1, 32, 64);
  ax2 += __shfl_xor(ax2, 32, 64);
  ax3 += __shfl_xor(ax3, 32, 64);
  if (half == 0) {
    uint2 o;
    o.x = pk16(ax0, ax1);
    o.y = pk16(ax2, ax3);
    ((uint2*)Z)[(size_t)n * 32 + l32] = o;
  }
}

// ======== LDS-free fp16 MFMA GEMM — r19: 32-way-split stats, 1 atomic/thread ========
// r18 (8-way split) confirmed the epilogue atomic-chain theory (-262 us). r19 deepens:
// gstat[32][256] (sum|sq fused into one 256-ch array), block adds into slot bid&31
// (chain ~25), each of 256 threads does exactly ONE atomic. Hierarchical counter
// cnt[0..31] + cnt[32] master. Last block sums 32 partials (unrolled, pipelined).
// MODE 0: a = A2u fp16 [M][128] direct (nt loads)
// MODE 1: a = relu(pa*x+pc), x = A2u fp16 (plain loads)
// MODE 2: a = 0.25*(A fp32 SKIP + relu(pa*y+pc)), y = A2u fp16
// MODE 3: a = (fp16)A, A fp32 [M][16], K=32 pad
// OUT 0: C fp32   OUT 1: C fp16 (plain — consumer reuses via cache)
template <int KTOT, int MODE, int OUT>
__global__ __launch_bounds__(256, 4) void gemm_mfma(
    const float* __restrict__ A, const ushort_t* __restrict__ A2u,
    const ushort_t* __restrict__ Bhi,
    const float* __restrict__ bias,
    const float* __restrict__ pa, const float* __restrict__ pc,
    void* __restrict__ Cv,
    float* __restrict__ gstat,
    float* __restrict__ aout, float* __restrict__ cout, int* __restrict__ cnt,
    const float* __restrict__ gamma, const float* __restrict__ beta,
    float invN, int M, int nb) {
  __shared__ float s_part[4][256];   // [wave][0..127]=sum, [128..255]=sumsq
  __shared__ int s_last;
  const int tid = threadIdx.x;
  const int w = tid >> 6;
  const int lane = tid & 63;
  const int ln = lane & 15;
  const int quad = lane >> 4;
  const int brow = blockIdx.x * 128;
  constexpr int AST = (MODE == 3) ? 16 : 128;

  int r0 = brow + (w << 5) + ln;       if (r0 >= M) r0 = M - 1;
  int r1 = brow + (w << 5) + 16 + ln;  if (r1 >= M) r1 = M - 1;

  f32x4 acc[2][8];
#pragma unroll
  for (int rt = 0; rt < 2; ++rt)
#pragma unroll
    for (int ct = 0; ct < 8; ++ct) acc[rt][ct] = (f32x4){0.0f, 0.0f, 0.0f, 0.0f};

  constexpr int KC = KTOT / 32;
#pragma unroll
  for (int kcl = 0; kcl < KC; ++kcl) {
    const int kb = (kcl << 5) + (quad << 3);
    f16x8 af0, af1;
    if constexpr (MODE == 0) {
      af0 = __builtin_bit_cast(f16x8, ntl_s8(A2u + (size_t)r0 * 128 + kb));
      af1 = __builtin_bit_cast(f16x8, ntl_s8(A2u + (size_t)r1 * 128 + kb));
    } else if constexpr (MODE == 1) {
      uint32x4 xa = *(const uint32x4*)(A2u + (size_t)r0 * 128 + kb);
      uint32x4 xb = *(const uint32x4*)(A2u + (size_t)r1 * 128 + kb);
      float4 p0 = *(const float4*)(pa + kb);
      float4 p1 = *(const float4*)(pa + kb + 4);
      float4 q0 = *(const float4*)(pc + kb);
      float4 q1 = *(const float4*)(pc + kb + 4);
      float pp[8] = {p0.x, p0.y, p0.z, p0.w, p1.x, p1.y, p1.z, p1.w};
      float qq[8] = {q0.x, q0.y, q0.z, q0.w, q1.x, q1.y, q1.z, q1.w};
      float e0[8] = {f16l(xa.x), f16h(xa.x), f16l(xa.y), f16h(xa.y),
                     f16l(xa.z), f16h(xa.z), f16l(xa.w), f16h(xa.w)};
      float e1[8] = {f16l(xb.x), f16h(xb.x), f16l(xb.y), f16h(xb.y),
                     f16l(xb.z), f16h(xb.z), f16l(xb.w), f16h(xb.w)};
#pragma unroll
      for (int j = 0; j < 8; ++j) {
        e0[j] = fmaxf(fmaf(pp[j], e0[j], qq[j]), 0.0f);
        e1[j] = fmaxf(fmaf(pp[j], e1[j], qq[j]), 0.0f);
      }
      af0 = pack8(e0);
      af1 = pack8(e1);
    } else if constexpr (MODE == 2) {
      f32x4 a0 = ntl4(A + (size_t)r0 * AST + kb);
      f32x4 a1 = ntl4(A + (size_t)r0 * AST + kb + 4);
      f32x4 b0 = ntl4(A + (size_t)r1 * AST + kb);
      f32x4 b1 = ntl4(A + (size_t)r1 * AST + kb + 4);
      float s0[8] = {a0.x, a0.y, a0.z, a0.w, a1.x, a1.y, a1.z, a1.w};
      float s1[8] = {b0.x, b0.y, b0.z, b0.w, b1.x, b1.y, b1.z, b1.w};
      uint32x4 ya = *(const uint32x4*)(A2u + (size_t)r0 * 128 + kb);
      uint32x4 yb = *(const uint32x4*)(A2u + (size_t)r1 * 128 + kb);
      float4 p0 = *(const float4*)(pa + kb);
      float4 p1 = *(const float4*)(pa + kb + 4);
      float4 q0 = *(const float4*)(pc + kb);
      float4 q1 = *(const float4*)(pc + kb + 4);
      float pp[8] = {p0.x, p0.y, p0.z, p0.w, p1.x, p1.y, p1.z, p1.w};
      float qq[8] = {q0.x, q0.y, q0.z, q0.w, q1.x, q1.y, q1.z, q1.w};
      float y0a[8] = {f16l(ya.x), f16h(ya.x), f16l(ya.y), f16h(ya.y),
                      f16l(ya.z), f16h(ya.z), f16l(ya.w), f16h(ya.w)};
      float y1a[8] = {f16l(yb.x), f16h(yb.x), f16l(yb.y), f16h(yb.y),
                      f16l(yb.z), f16h(yb.z), f16l(yb.w), f16h(yb.w)};
      float e0[8], e1[8];
#pragma unroll
      for (int j = 0; j < 8; ++j) {
        e0[j] = 0.25f * (s0[j] + fmaxf(fmaf(pp[j], y0a[j], qq[j]), 0.0f));
        e1[j] = 0.25f * (s1[j] + fmaxf(fmaf(pp[j], y1a[j], qq[j]), 0.0f));
      }
      af0 = pack8(e0);
      af1 = pack8(e1);
    } else {  // MODE 3
      if (kb < 16) {
        f32x4 a0 = ntl4(A + (size_t)r0 * AST + kb);
        f32x4 a1 = ntl4(A + (size_t)r0 * AST + kb + 4);
        f32x4 b0 = ntl4(A + (size_t)r1 * AST + kb);
        f32x4 b1 = ntl4(A + (size_t)r1 * AST + kb + 4);
        float e0[8] = {a0.x, a0.y, a0.z, a0.w, a1.x, a1.y, a1.z, a1.w};
        float e1[8] = {b0.x, b0.y, b0.z, b0.w, b1.x, b1.y, b1.z, b1.w};
        af0 = pack8(e0);
        af1 = pack8(e1);
      } else {
#pragma unroll
        for (int j = 0; j < 8; ++j) { af0[j] = (_Float16)0.0f; af1[j] = (_Float16)0.0f; }
      }
    }
    const ushort_t* bh_base = Bhi + (((size_t)(kcl << 9) + lane) << 3);
#pragma unroll
    for (int ct = 0; ct < 8; ++ct) {
      f16x8 bh = __builtin_bit_cast(f16x8, *(const short8*)(bh_base + (ct << 9)));
      acc[0][ct] = __builtin_amdgcn_mfma_f32_16x16x32_f16(af0, bh, acc[0][ct], 0, 0, 0);
      acc[1][ct] = __builtin_amdgcn_mfma_f32_16x16x32_f16(af1, bh, acc[1][ct], 0, 0, 0);
    }
  }

  // ---- epilogue: bias, store, quad-shuffle stats ----
#pragma unroll
  for (int ct = 0; ct < 8; ++ct) {
    int col = (ct << 4) + ln;
    float bsc = bias[col];
    float csum = 0.0f, csq = 0.0f;
#pragma unroll
    for (int rt = 0; rt < 2; ++rt) {
#pragma unroll
      for (int i = 0; i < 4; ++i) {
        int row = brow + (w << 5) + (rt << 4) + (quad << 2) + i;
        if (row < M) {
          float y = acc[rt][ct][i] + bsc;
          csum += y; csq += y * y;
          if constexpr (OUT == 0) {
            ((float*)Cv)[(size_t)row * 128 + col] = y;
          } else {
            ((ushort_t*)Cv)[(size_t)row * 128 + col] = f2h(y);
          }
        }
      }
    }
    csum += __shfl_xor(csum, 16, 64);
    csum += __shfl_xor(csum, 32, 64);
    csq += __shfl_xor(csq, 16, 64);
    csq += __shfl_xor(csq, 32, 64);
    if (quad == 0) {
      s_part[w][col] = csum;
      s_part[w][128 + col] = csq;
    }
  }
  __syncthreads();
  const int cls = (int)(blockIdx.x & (NCLS - 1));
  {
    // one atomic per thread: ch 0..127 = sum, 128..255 = sumsq
    float v = s_part[0][tid] + s_part[1][tid] + s_part[2][tid] + s_part[3][tid];
    atomicAdd(&gstat[(cls << 8) + tid], v);
  }
  __syncthreads();   // drains vmcnt -> stats atomics complete
  if (tid == 0) {
    s_last = 0;
    int clsCnt = (nb >> 5) + ((cls < (nb & (NCLS - 1))) ? 1 : 0);
    int v = __hip_atomic_fetch_add(&cnt[cls], 1, __ATOMIC_RELAXED, __HIP_MEMORY_SCOPE_AGENT);
    if (v == clsCnt - 1) {   // last of this class -> bump master
      int vm = __hip_atomic_fetch_add(&cnt[NCLS], 1, __ATOMIC_RELAXED, __HIP_MEMORY_SCOPE_AGENT);
      if (vm == NCLS - 1) s_last = 1;
    }
  }
  __syncthreads();
  if (s_last && tid < 128) {
    float s = 0.0f, q = 0.0f;
#pragma unroll
    for (int c = 0; c < NCLS; ++c) {
      s += __hip_atomic_load(&gstat[(c << 8) + tid], __ATOMIC_RELAXED, __HIP_MEMORY_SCOPE_AGENT);
      q += __hip_atomic_load(&gstat[(c << 8) + 128 + tid], __ATOMIC_RELAXED,
                             __HIP_MEMORY_SCOPE_AGENT);
    }
    float mu = s * invN;
    float var = q * invN - mu * mu;
    float sc = gamma[tid] * rsqrtf(var + BN_EPS);
    aout[tid] = sc;
    cout[tid] = beta[tid] - sc * mu;
  }
}

// ============================ regressor head ============================
// r19: reads fp16 head output (head GEMM now OUT 1 -> halves its C write + this read)
__global__ __launch_bounds__(256) void finaldot_kernel(
    const ushort_t* __restrict__ Y, const float* __restrict__ a, const float* __restrict__ c,
    const float* __restrict__ Wr2, const float* __restrict__ br2,
    float* __restrict__ out, int N) {
  int wv = threadIdx.x >> 6;
  int lane = threadIdx.x & 63;
  int n = blockIdx.x * 4 + wv;
  if (n >= N) return;
  uint_t yv = ((const uint_t*)Y)[(size_t)n * 64 + lane];
  int c0 = lane * 2;
  float s = fmaxf(fmaf(a[c0], f16l(yv), c[c0]), 0.0f) * Wr2[c0] +
            fmaxf(fmaf(a[c0 + 1], f16h(yv), c[c0 + 1]), 0.0f) * Wr2[c0 + 1];
  for (int off = 32; off > 0; off >>= 1) s += __shfl_down(s, off, 64);
  if (lane == 0) out[n] = 1.0f / (1.0f + expf(-(s + br2[0])));
}

// ============================ launch ============================
extern "C" void kernel_launch(void* const* d_in, const int* in_sizes, int n_in,
                              void* d_out, int out_size, void* d_ws, size_t ws_size,
                              hipStream_t stream) {
  const float* x     = (const float*)d_in[0];
  const int*   ei    = (const int*)d_in[1];
  const float* eps   = (const float*)d_in[2];
  const float* W1_0  = (const float*)d_in[3];
  const float* b1_0  = (const float*)d_in[4];
  const float* W1    = (const float*)d_in[5];
  const float* b1    = (const float*)d_in[6];
  const float* g_in  = (const float*)d_in[7];
  const float* be_in = (const float*)d_in[8];
  const float* W2    = (const float*)d_in[9];
  const float* b2    = (const float*)d_in[10];
  const float* g_out = (const float*)d_in[11];
  const float* be_out= (const float*)d_in[12];
  const float* Wr1   = (const float*)d_in[13];
  const float* br1   = (const float*)d_in[14];
  const float* gr    = (const float*)d_in[15];
  const float* ber   = (const float*)d_in[16];
  const float* Wr2   = (const float*)d_in[17];
  const float* br2   = (const float*)d_in[18];
  float* out = (float*)d_out;

  const int N = in_sizes[0] / IN_F;   // 100000
  const int E = in_sizes[1] / 2;      // 1600000
  const int* srcv = ei;
  const int* dstv = ei + E;
  const int nbk = (N + 511) >> 9;     // 196 buckets

  // workspace carve (arena slots widened for 32-way split stats, r19)
  float* X0    = (float*)d_ws;                  // [N][128] fp32-sized (fp16 Z/H1/head)
  float* SKIP  = X0 + (size_t)N * HID;          // [N][128] fp32 (L0 [N,16] temp, then skip)
  ushort_t* YB = (ushort_t*)(SKIP + (size_t)N * HID);  // [N][128] fp16 Y (hot gather target)
  int* colb    = (int*)(YB + (size_t)N * HID);
  int* row_ptr = colb + E;
  int2* ebuf   = (int2*)(row_ptr + (N + 4));
  int* bucketCnt  = (int*)(ebuf + E);
  int* bucketBase = bucketCnt + 256;
  int* bucketCur  = bucketBase + 260;
  // arena: 17 slots x 8512 floats:
  //   [0..8191] gstat[32][256] | [8192..8319] SA | [8320..8447] SC
  //   [8448..8480] cnt[33] | pad to 8512
  float* arena = (float*)(bucketCur + 256);
  ushort_t* WB = (ushort_t*)(arena + 17 * 8512); // hi blob (fp16)
  ushort_t* X0u = (ushort_t*)X0;

  hipMemsetAsync(bucketCnt, 0, sizeof(int) * 256, stream);
  hipMemsetAsync(arena, 0, sizeof(float) * 17 * 8512, stream);

  // CSR build (bucket sort)
  int nbE = (E + 2047) / 2048;
  bhist_kernel<<<nbE, 256, 0, stream>>>(dstv, bucketCnt, E, nbk);
  bscan_kernel<<<1, 256, 0, stream>>>(bucketCnt, bucketBase, bucketCur, row_ptr, N, E, nbk);
  bscatter_kernel<<<nbE, 256, 0, stream>>>(srcv, dstv, bucketCur, ebuf, E, nbk);
  bcsr_kernel<<<nbk, 256, 0, stream>>>(ebuf, bucketBase, row_ptr, colb, N);
  preconv_kernel<<<dim3(64, 17), 256, 0, stream>>>(W1_0, W1, W2, Wr1, WB);

  const int gg = (N + 127) / 128;   // 128-row tiles (r10 optimum)
  const float invN = 1.0f / (float)N;
#define SLOT(s) (arena + (s) * 8512)
#define SSTAT(s) SLOT(s)
#define SA(s)   (SLOT(s) + 8192)
#define SC(s)   (SLOT(s) + 8320)
#define SCNT(s) ((int*)(SLOT(s) + 8448))
#define WBH(g)  (WB + ((g) == 0 ? 0 : (8192 + (size_t)((g) - 1) * 32768)))

  // ---- layer 0 ----  agg16: x -> SKIP[N,16] fp32; g0a: SKIP -> X0u fp16; g0b: X0u -> YB fp16
  agg16_kernel<<<(N + 31) / 32, 256, 0, stream>>>(x, row_ptr, colb, eps, SKIP, N);
  gemm_mfma<32, 3, 1><<<gg, 256, 0, stream>>>(
      SKIP, nullptr, WBH(0), b1_0, nullptr, nullptr, X0u,
      SSTAT(0), SA(0), SC(0), SCNT(0), g_in, be_in, invN, N, gg);
  gemm_mfma<128, 1, 1><<<gg, 256, 0, stream>>>(
      nullptr, X0u, WBH(8), b2, SA(0), SC(0), YB,
      SSTAT(1), SA(1), SC(1), SCNT(1), g_out, be_out, invN, N, gg);
  // No SKIP memset: L=2's agg does a plain store (smode=1) covering all N*128 elements.

  // ---- layers 1..7 ----  agg: YB->X0u (fp16 Z); gemm1: X0u->X0u in place; gemm2: X0u->YB
  for (int L = 1; L < NLAYERS; ++L) {
    int sp = 2 * L - 1;
    int s0 = 2 * L, s1 = 2 * L + 1;
    // skip taps h_1,h_3,h_5 at L=2,4,6 (h_7 folded in regressor). First tap stores.
    int smode = ((L - 1) & 1) ? ((L == 2) ? 1 : 2) : 0;
    agg128_kernel<<<(N + 3) / 4, 256, 0, stream>>>(
        YB, SA(sp), SC(sp), row_ptr, colb, eps, L, (uint_t*)X0u, SKIP, smode, N);
    gemm_mfma<128, 0, 1><<<gg, 256, 0, stream>>>(
        nullptr, X0u, WBH(L), b1 + (size_t)(L - 1) * HID, nullptr, nullptr, X0u,
        SSTAT(s0), SA(s0), SC(s0), SCNT(s0),
        g_in + (size_t)L * HID, be_in + (size_t)L * HID, invN, N, gg);
    gemm_mfma<128, 1, 1><<<gg, 256, 0, stream>>>(
        nullptr, X0u, WBH(8 + L), b2 + (size_t)L * HID, SA(s0), SC(s0), YB,
        SSTAT(s1), SA(s1), SC(s1), SCNT(s1),
        g_out + (size_t)L * HID, be_out + (size_t)L * HID, invN, N, gg);
  }
  // Y7 in YB (fp16), slot 15 holds its outer-BN params

  // ---- regressor: op = 0.25*(SKIP + relu(a7*Y7+c7)); head output fp16 into X0u ----
  gemm_mfma<128, 2, 1><<<gg, 256, 0, stream>>>(
      SKIP, YB, WBH(16), br1, SA(15), SC(15), X0u,
      SSTAT(16), SA(16), SC(16), SCNT(16), gr, ber, invN, N, gg);
  finaldot_kernel<<<(N + 3) / 4, 256, 0, stream>>>(X0u, SA(16), SC(16), Wr2, br2, out, N);
#undef SLOT
#undef SSTAT
#undef SA
#undef SC
#undef SCNT
#undef WBH
}